// Round 1
// baseline (1981.401 us; speedup 1.0000x reference)
//
#include <hip/hip_runtime.h>
#include <hip/hip_bf16.h>

#define N_NODES 50000
#define N_EDGES 400000
#define NB 64

typedef unsigned short u16;
typedef __attribute__((ext_vector_type(8))) short s16x8;
typedef __attribute__((ext_vector_type(4))) float f32x4;

__device__ __forceinline__ u16 f2b(float f) {
  __hip_bfloat16 h = __float2bfloat16(f);
  return *reinterpret_cast<const u16*>(&h);
}

struct Seg { const u16* src; int width; const int* idx; };

// ---------------- elementwise f32 -> bf16 ----------------
__global__ void k_f2b(const float* __restrict__ in, u16* __restrict__ out, int n) {
  int i = blockIdx.x * 256 + threadIdx.x;
  if (i < n) out[i] = f2b(in[i]);
}

// ---------------- weight transpose-convert: Wt[n*K + k] = bf16(W[k*N + n]) ----------------
__global__ void k_wt(const float* __restrict__ W, u16* __restrict__ Wt, int K, int N) {
  int i = blockIdx.x * 256 + threadIdx.x;
  if (i >= K * N) return;
  int k = i % K, n = i / K;
  Wt[n * K + k] = f2b(W[(size_t)k * N + n]);
}

// ---------------- generic gather-concat GEMM, bf16 MFMA ----------------
// C[M,BN] = concat(segments)[M,K] @ Wt^T + bias
// EPI 0: store bf16; EPI 1: store f32 + bf16; EPI 2: atomicAdd into sdst[sidx[row]*BN + col]
template<int BN, int EPI>
__global__ __launch_bounds__(256)
void gemm_gather(const u16* __restrict__ Wt, const float* __restrict__ bias,
                 Seg s0, Seg s1, Seg s2, int M, int K,
                 float* __restrict__ outf, u16* __restrict__ outb,
                 const int* __restrict__ sidx, float* __restrict__ sdst)
{
  constexpr int BM = 128;
  constexpr int LDA = 72;            // 64 + 8 pad -> 16B-aligned rows, 2-way banks (free)
  __shared__ u16 As[BM * LDA];
  __shared__ u16 Bs[BN * LDA];

  const int t = threadIdx.x;
  const int wv = t >> 6;             // wave 0..3, owns rows [wv*32, wv*32+32)
  const int lane = t & 63;
  const int lr = lane & 15;
  const int lg = lane >> 4;
  const int bm0 = blockIdx.x * BM;

  f32x4 acc[2][BN / 16];
#pragma unroll
  for (int a = 0; a < 2; ++a)
#pragma unroll
    for (int b = 0; b < BN / 16; ++b)
      acc[a][b] = (f32x4){0.f, 0.f, 0.f, 0.f};

  // A staging geometry: thread stages 32 bf16 of row ar at k-offset ako
  const int ar = t & 127;
  const int ako = (t >> 7) * 32;
  int agrow = bm0 + ar;
  if (agrow >= M) agrow = M - 1;     // clamp (stores masked later)

  // B staging geometry
  constexpr int BPT = (BN * 64) / 256;                 // elems per thread: 32 or 16
  const int bn  = (BN == 128) ? (t & 127) : (t & 63);
  const int bko = (BN == 128) ? ((t >> 7) * 32) : ((t >> 6) * 16);

  for (int k0 = 0; k0 < K; k0 += 64) {
    // segment select (segment widths are multiples of 64, chunk never straddles)
    const Seg* sg; int segk;
    if (k0 < s0.width) { sg = &s0; segk = k0; }
    else if (k0 < s0.width + s1.width) { sg = &s1; segk = k0 - s0.width; }
    else { sg = &s2; segk = k0 - s0.width - s1.width; }

    int srow = sg->idx ? sg->idx[agrow] : agrow;
    const u16* ap = sg->src + (size_t)srow * sg->width + segk + ako;
    uint4 av[4];
#pragma unroll
    for (int j = 0; j < 4; ++j) av[j] = *reinterpret_cast<const uint4*>(ap + j * 8);

    const u16* bp = Wt + (size_t)bn * K + k0 + bko;
    uint4 bv[BPT / 8];
#pragma unroll
    for (int j = 0; j < BPT / 8; ++j) bv[j] = *reinterpret_cast<const uint4*>(bp + j * 8);

    __syncthreads();   // previous compute done before LDS overwrite
#pragma unroll
    for (int j = 0; j < 4; ++j)
      *reinterpret_cast<uint4*>(&As[ar * LDA + ako + j * 8]) = av[j];
#pragma unroll
    for (int j = 0; j < BPT / 8; ++j)
      *reinterpret_cast<uint4*>(&Bs[bn * LDA + bko + j * 8]) = bv[j];
    __syncthreads();   // tiles visible

#pragma unroll
    for (int kk = 0; kk < 64; kk += 32) {
      s16x8 af[2];
#pragma unroll
      for (int rf = 0; rf < 2; ++rf)
        af[rf] = *reinterpret_cast<const s16x8*>(&As[(wv * 32 + rf * 16 + lr) * LDA + kk + lg * 8]);
#pragma unroll
      for (int f = 0; f < BN / 16; ++f) {
        s16x8 bf = *reinterpret_cast<const s16x8*>(&Bs[(f * 16 + lr) * LDA + kk + lg * 8]);
        acc[0][f] = __builtin_amdgcn_mfma_f32_16x16x32_bf16(af[0], bf, acc[0][f], 0, 0, 0);
        acc[1][f] = __builtin_amdgcn_mfma_f32_16x16x32_bf16(af[1], bf, acc[1][f], 0, 0, 0);
      }
    }
  }

  // epilogue: C/D layout col = lane&15, row = (lane>>4)*4 + reg (verified m89/m91)
  float bvz[BN / 16];
#pragma unroll
  for (int f = 0; f < BN / 16; ++f) bvz[f] = bias[f * 16 + lr];

#pragma unroll
  for (int rf = 0; rf < 2; ++rf) {
#pragma unroll
    for (int rr = 0; rr < 4; ++rr) {
      int grow = bm0 + wv * 32 + rf * 16 + lg * 4 + rr;
      if (EPI != 2 && grow >= M) continue;
      int drow = (EPI == 2) ? sidx[grow] : grow;
#pragma unroll
      for (int f = 0; f < BN / 16; ++f) {
        float v = acc[rf][f][rr] + bvz[f];
        int col = f * 16 + lr;
        if (EPI == 0) {
          outb[(size_t)grow * BN + col] = f2b(v);
        } else if (EPI == 1) {
          outf[(size_t)grow * BN + col] = v;
          outb[(size_t)grow * BN + col] = f2b(v);
        } else {
          atomicAdd(&sdst[(size_t)drow * BN + col], v);
        }
      }
    }
  }
}

// ---------------- sorted-batch pooling: dst[batch[n]][c] += src[n][c] ----------------
__global__ void k_pool(const float* __restrict__ src, const int* __restrict__ batch,
                       float* __restrict__ dst, int n) {
  int c = threadIdx.x;               // 0..127
  int n0 = blockIdx.x * 128;
  if (n0 >= n) return;
  int n1 = n0 + 128; if (n1 > n) n1 = n;
  float acc = 0.f;
  int cur = batch[n0];
  for (int i = n0; i < n1; ++i) {
    int bi = batch[i];
    if (bi != cur) { atomicAdd(&dst[cur * 128 + c], acc); acc = 0.f; cur = bi; }
    acc += src[(size_t)i * 128 + c];
  }
  atomicAdd(&dst[cur * 128 + c], acc);
}

// ---------------- tiny fp32 GEMM: out[M,N] = concat(A0,A1)[M,K] @ W[K,N] + b ----------------
__global__ void k_small(const float* __restrict__ A0, int w0,
                        const float* __restrict__ A1, int w1,
                        const float* __restrict__ W, const float* __restrict__ b,
                        float* __restrict__ out, int N, int K) {
  int r = blockIdx.x, c = threadIdx.x;
  if (c >= N) return;
  float acc = b[c];
  for (int k = 0; k < K; ++k) {
    float a = (k < w0) ? A0[r * w0 + k] : A1[r * w1 + (k - w0)];
    acc = fmaf(a, W[(size_t)k * N + c], acc);
  }
  out[(size_t)r * N + c] = acc;
}

extern "C" void kernel_launch(void* const* d_in, const int* in_sizes, int n_in,
                              void* d_out, int out_size, void* d_ws, size_t ws_size,
                              hipStream_t stream) {
  const float* x     = (const float*)d_in[0];
  const int*   eidx  = (const int*)d_in[1];
  const float* eattr = (const float*)d_in[2];
  const int*   batch = (const int*)d_in[3];
  const float* eW0 = (const float*)d_in[4];  const float* eb0 = (const float*)d_in[5];
  const float* eW1 = (const float*)d_in[6];  const float* eb1 = (const float*)d_in[7];
  const float* n1W0 = (const float*)d_in[8]; const float* n1b0 = (const float*)d_in[9];
  const float* n1W1 = (const float*)d_in[10];const float* n1b1 = (const float*)d_in[11];
  const float* n2W0 = (const float*)d_in[12];const float* n2b0 = (const float*)d_in[13];
  const float* n2W1 = (const float*)d_in[14];const float* n2b1 = (const float*)d_in[15];
  const float* g1W0 = (const float*)d_in[16];const float* g1b0 = (const float*)d_in[17];
  const float* g1W1 = (const float*)d_in[18];const float* g1b1 = (const float*)d_in[19];
  const float* g2W0 = (const float*)d_in[20];const float* g2b0 = (const float*)d_in[21];
  const float* g2W1 = (const float*)d_in[22];const float* g2b1 = (const float*)d_in[23];
  const float* fW0 = (const float*)d_in[24]; const float* fb0 = (const float*)d_in[25];
  const float* fW1 = (const float*)d_in[26]; const float* fb1 = (const float*)d_in[27];

  const int* row  = eidx;
  const int* colv = eidx + N_EDGES;

  char* ws = (char*)d_ws;
  size_t off = 0;
  auto alloc = [&](size_t bytes) -> void* {
    void* p = ws + off; off = (off + bytes + 255) & ~(size_t)255; return p;
  };
  u16*   x_b   = (u16*)alloc((size_t)N_NODES * 128 * 2);
  u16*   ea_b  = (u16*)alloc((size_t)N_EDGES * 64 * 2);
  u16*   h_b   = (u16*)alloc((size_t)N_EDGES * 128 * 2);
  float* agg_f = (float*)alloc((size_t)N_NODES * 128 * 4);   // reused as gagg
  u16*   agg_b = (u16*)alloc((size_t)N_NODES * 128 * 2);
  float* x_f   = (float*)alloc((size_t)N_NODES * 128 * 4);
  u16*   wt    = (u16*)alloc((size_t)180224 * 2);
  float* npool = (float*)alloc((size_t)NB * 128 * 4);
  float* mpool = (float*)alloc((size_t)NB * 128 * 4);
  float* su0   = (float*)alloc((size_t)NB * 128 * 4);
  float* su1   = (float*)alloc((size_t)NB * 128 * 4);
  float* su2   = (float*)alloc((size_t)NB * 256 * 4);
  (void)ws_size; (void)in_sizes; (void)n_in; (void)out_size;

  u16* eW0t  = wt + 0;
  u16* eW1t  = wt + 40960;
  u16* n1W0t = wt + 49152;
  u16* n1W1t = wt + 73728;
  u16* n2W0t = wt + 90112;
  u16* n2W1t = wt + 122880;
  u16* g1W0t = wt + 139264;
  u16* g1W1t = wt + 163840;

  // input conversions
  k_f2b<<<(N_NODES * 128 + 255) / 256, 256, 0, stream>>>(x, x_b, N_NODES * 128);
  k_f2b<<<(N_EDGES * 64 + 255) / 256, 256, 0, stream>>>(eattr, ea_b, N_EDGES * 64);
  k_wt<<<(320 * 128 + 255) / 256, 256, 0, stream>>>(eW0, eW0t, 320, 128);
  k_wt<<<(128 * 64 + 255) / 256, 256, 0, stream>>>(eW1, eW1t, 128, 64);
  k_wt<<<(192 * 128 + 255) / 256, 256, 0, stream>>>(n1W0, n1W0t, 192, 128);
  k_wt<<<(128 * 128 + 255) / 256, 256, 0, stream>>>(n1W1, n1W1t, 128, 128);
  k_wt<<<(256 * 128 + 255) / 256, 256, 0, stream>>>(n2W0, n2W0t, 256, 128);
  k_wt<<<(128 * 128 + 255) / 256, 256, 0, stream>>>(n2W1, n2W1t, 128, 128);
  k_wt<<<(192 * 128 + 255) / 256, 256, 0, stream>>>(g1W0, g1W0t, 192, 128);
  k_wt<<<(128 * 128 + 255) / 256, 256, 0, stream>>>(g1W1, g1W1t, 128, 128);

  Seg zs{nullptr, 0, nullptr};
  const int GE = N_EDGES / 128;            // 3125 (exact)
  const int GN = (N_NODES + 127) / 128;    // 391

  for (int it = 0; it < 2; ++it) {
    // S1: h = cat(x[row], x[col], ea) @ eW0 + eb0
    gemm_gather<128, 0><<<GE, 256, 0, stream>>>(eW0t, eb0,
        Seg{x_b, 128, row}, Seg{x_b, 128, colv}, Seg{ea_b, 64, nullptr},
        N_EDGES, 320, nullptr, h_b, nullptr, nullptr);
    // S2: ea = h @ eW1 + eb1
    gemm_gather<64, 0><<<GE, 256, 0, stream>>>(eW1t, eb1,
        Seg{h_b, 128, nullptr}, zs, zs, N_EDGES, 128, nullptr, ea_b, nullptr, nullptr);
    // S3: h = cat(x[row], ea) @ n1W0 + n1b0
    gemm_gather<128, 0><<<GE, 256, 0, stream>>>(n1W0t, n1b0,
        Seg{x_b, 128, row}, Seg{ea_b, 64, nullptr}, zs,
        N_EDGES, 192, nullptr, h_b, nullptr, nullptr);
    // S4: agg[col] += h @ n1W1 + n1b1
    hipMemsetAsync(agg_f, 0, (size_t)N_NODES * 128 * 4, stream);
    gemm_gather<128, 2><<<GE, 256, 0, stream>>>(n1W1t, n1b1,
        Seg{h_b, 128, nullptr}, zs, zs, N_EDGES, 128, nullptr, nullptr, colv, agg_f);
    k_f2b<<<(N_NODES * 128 + 255) / 256, 256, 0, stream>>>(agg_f, agg_b, N_NODES * 128);
    // S5: h = cat(x, agg) @ n2W0 + n2b0
    gemm_gather<128, 0><<<GN, 256, 0, stream>>>(n2W0t, n2b0,
        Seg{x_b, 128, nullptr}, Seg{agg_b, 128, nullptr}, zs,
        N_NODES, 256, nullptr, h_b, nullptr, nullptr);
    // S6: x = h @ n2W1 + n2b1  (write f32 + bf16)
    gemm_gather<128, 1><<<GN, 256, 0, stream>>>(n2W1t, n2b1,
        Seg{h_b, 128, nullptr}, zs, zs, N_NODES, 128, x_f, x_b, nullptr, nullptr);
  }

  // GlobalModel — only the last iteration's result matters
  // S7: h = cat(x[row], ea) @ g1W0 + g1b0
  gemm_gather<128, 0><<<GE, 256, 0, stream>>>(g1W0t, g1b0,
      Seg{x_b, 128, row}, Seg{ea_b, 64, nullptr}, zs,
      N_EDGES, 192, nullptr, h_b, nullptr, nullptr);
  // S8: gagg[col] += h @ g1W1 + g1b1
  hipMemsetAsync(agg_f, 0, (size_t)N_NODES * 128 * 4, stream);
  gemm_gather<128, 2><<<GE, 256, 0, stream>>>(g1W1t, g1b1,
      Seg{h_b, 128, nullptr}, zs, zs, N_EDGES, 128, nullptr, nullptr, colv, agg_f);

  // pools (batch is sorted)
  hipMemsetAsync(npool, 0, (size_t)NB * 128 * 4, stream);
  hipMemsetAsync(mpool, 0, (size_t)NB * 128 * 4, stream);
  k_pool<<<GN, 128, 0, stream>>>(x_f, batch, npool, N_NODES);
  k_pool<<<GN, 128, 0, stream>>>(agg_f, batch, mpool, N_NODES);

  // global MLP + final MLP (tiny, fp32)
  k_small<<<NB, 128, 0, stream>>>(npool, 128, mpool, 128, g2W0, g2b0, su0, 128, 256);
  k_small<<<NB, 128, 0, stream>>>(su0, 128, nullptr, 0, g2W1, g2b1, su1, 128, 128);
  k_small<<<NB, 256, 0, stream>>>(su1, 128, nullptr, 0, fW0, fb0, su2, 256, 128);
  k_small<<<NB, 64, 0, stream>>>(su2, 256, nullptr, 0, fW1, fb1, (float*)d_out, 1, 256);
}

// Round 3
// 1324.910 us; speedup vs baseline: 1.4955x; 1.4955x over previous
//
#include <hip/hip_runtime.h>
#include <hip/hip_bf16.h>

#define N_NODES 50000
#define N_EDGES 400000
#define NB 64

typedef unsigned short u16;
typedef unsigned int u32;
typedef __attribute__((ext_vector_type(8))) short s16x8;
typedef __attribute__((ext_vector_type(4))) float f32x4;

__device__ __forceinline__ u16 f2b(float f) {
  __hip_bfloat16 h = __float2bfloat16(f);
  return *reinterpret_cast<const u16*>(&h);
}
__device__ __forceinline__ float b2f(u16 u) {
  u32 v = ((u32)u) << 16;
  return *reinterpret_cast<const float*>(&v);
}

struct Seg { const u16* src; int width; };

// ---------------- elementwise f32 -> bf16 ----------------
__global__ void k_f2b(const float* __restrict__ in, u16* __restrict__ out, int n) {
  int i = blockIdx.x * 256 + threadIdx.x;
  if (i < n) out[i] = f2b(in[i]);
}

// ---------------- weight transpose-convert: Wt[n*K + k] = bf16(W[k*N + n]) ----------------
__global__ void k_wt(const float* __restrict__ W, u16* __restrict__ Wt, int K, int N) {
  int i = blockIdx.x * 256 + threadIdx.x;
  if (i >= K * N) return;
  int k = i % K, n = i / K;
  Wt[n * K + k] = f2b(W[(size_t)k * N + n]);
}

// ---------------- CSR build over col ----------------
__global__ void k_hist(const int* __restrict__ colv, int* __restrict__ deg) {
  int i = blockIdx.x * 256 + threadIdx.x;
  if (i < N_EDGES) atomicAdd(&deg[colv[i]], 1);
}

__global__ void k_scan(const int* __restrict__ deg, int* __restrict__ rowptr, int n) {
  __shared__ int part[1024];
  int t = threadIdx.x;
  int chunk = (n + 1023) / 1024;
  int lo = t * chunk, hi = lo + chunk; if (hi > n) hi = n;
  if (lo > n) lo = n;
  int s = 0;
  for (int i = lo; i < hi; ++i) s += deg[i];
  part[t] = s;
  __syncthreads();
  for (int d = 1; d < 1024; d <<= 1) {
    int v = (t >= d) ? part[t - d] : 0;
    __syncthreads();
    part[t] += v;
    __syncthreads();
  }
  int base = (t == 0) ? 0 : part[t - 1];
  for (int i = lo; i < hi; ++i) { rowptr[i] = base; base += deg[i]; }
  if (t == 1023) rowptr[n] = part[1023];
}

__global__ void k_fill(const int* __restrict__ rowv, const int* __restrict__ colv,
                       int* __restrict__ cursor, int* __restrict__ crow, int* __restrict__ ceid) {
  int i = blockIdx.x * 256 + threadIdx.x;
  if (i >= N_EDGES) return;
  int pos = atomicAdd(&cursor[colv[i]], 1);
  crow[pos] = rowv[i];
  ceid[pos] = i;
}

__global__ void k_deg(const int* __restrict__ rowptr, float* __restrict__ degf) {
  int i = blockIdx.x * 256 + threadIdx.x;
  if (i < N_NODES) degf[i] = (float)(rowptr[i + 1] - rowptr[i]);
}

// ---------------- CSR gather-aggregate: adjX[v]=sum x[row_e], aggE[v]=sum ea_e ----------------
template<bool DOX, bool DOE>
__global__ void k_agg(const u16* __restrict__ xb, const u16* __restrict__ eab,
                      const int* __restrict__ rowptr, const int* __restrict__ crow,
                      const int* __restrict__ ceid,
                      u16* __restrict__ outX, u16* __restrict__ outE) {
  int wpb = blockDim.x >> 6;
  int w = blockIdx.x * wpb + (threadIdx.x >> 6);
  int l = threadIdx.x & 63;
  int nw = gridDim.x * wpb;
  for (int v = w; v < N_NODES; v += nw) {
    int s = rowptr[v], e1 = rowptr[v + 1];
    float ax0 = 0.f, ax1 = 0.f, ae = 0.f;
    for (int i = s; i < e1; ++i) {
      if (DOX) {
        int r = crow[i];
        u32 xv = *reinterpret_cast<const u32*>(&xb[(size_t)r * 128 + l * 2]);
        ax0 += b2f((u16)(xv & 0xffff));
        ax1 += b2f((u16)(xv >> 16));
      }
      if (DOE) {
        int e = ceid[i];
        ae += b2f(eab[(size_t)e * 64 + l]);
      }
    }
    if (DOX) {
      u32 pk = ((u32)f2b(ax1) << 16) | (u32)f2b(ax0);
      *reinterpret_cast<u32*>(&outX[(size_t)v * 128 + l * 2]) = pk;
    }
    if (DOE) outE[(size_t)v * 64 + l] = f2b(ae);
  }
}

// ---------------- fused EdgeModel: ea = (cat(x[row],x[col],ea)@eW0+eb0)@eW1+eb1 ----------------
// Stage-1 tiles use stride LDA=72 (K-chunk 64). Stage-2 h (128 cols) uses stride LDH=136.
__global__ __launch_bounds__(256)
void k_edge(const u16* __restrict__ xb, u16* __restrict__ eab,
            const int* __restrict__ rowv, const int* __restrict__ colv,
            const u16* __restrict__ eW0t, const float* __restrict__ eb0,
            const u16* __restrict__ eW1t, const float* __restrict__ eb1)
{
  constexpr int LDA = 72;    // stage-1 row stride (64 + 8 pad)
  constexpr int LDH = 136;   // stage-2 row stride (128 + 8 pad), 272B rows stay 16B-aligned
  __shared__ u16 As[128 * LDH];   // stage1: 128x72 region; stage2: h 128x136
  __shared__ u16 Bs[128 * LDA];   // stage1: B 128x72; stage2: eW1 64x136 (8704 <= 9216)
  const int t = threadIdx.x;
  const int wv = t >> 6, lane = t & 63, lr = lane & 15, lg = lane >> 4;
  const int bm0 = blockIdx.x * 128;

  f32x4 acc[2][8];
#pragma unroll
  for (int a = 0; a < 2; ++a)
#pragma unroll
    for (int b = 0; b < 8; ++b) acc[a][b] = (f32x4){0.f, 0.f, 0.f, 0.f};

  const int ar = t & 127;
  const int ako = (t >> 7) * 32;
  const int er = bm0 + ar;
  const int r_ = rowv[er], c_ = colv[er];

  const int bn = t & 127, bko = (t >> 7) * 32;

  // ---- stage 1: h = cat(x[row], x[col], ea) @ eW0 ----
  for (int c = 0; c < 5; ++c) {
    const u16* ap;
    if (c < 2)      ap = &xb[(size_t)r_ * 128 + c * 64 + ako];
    else if (c < 4) ap = &xb[(size_t)c_ * 128 + (c - 2) * 64 + ako];
    else            ap = &eab[(size_t)er * 64 + ako];
    uint4 av[4];
#pragma unroll
    for (int j = 0; j < 4; ++j) av[j] = *reinterpret_cast<const uint4*>(ap + j * 8);

    const u16* bp = eW0t + (size_t)bn * 320 + c * 64 + bko;
    uint4 bv[4];
#pragma unroll
    for (int j = 0; j < 4; ++j) bv[j] = *reinterpret_cast<const uint4*>(bp + j * 8);

    __syncthreads();
#pragma unroll
    for (int j = 0; j < 4; ++j)
      *reinterpret_cast<uint4*>(&As[ar * LDA + ako + j * 8]) = av[j];
#pragma unroll
    for (int j = 0; j < 4; ++j)
      *reinterpret_cast<uint4*>(&Bs[bn * LDA + bko + j * 8]) = bv[j];
    __syncthreads();

#pragma unroll
    for (int kk = 0; kk < 64; kk += 32) {
      s16x8 af[2];
#pragma unroll
      for (int rf = 0; rf < 2; ++rf)
        af[rf] = *reinterpret_cast<const s16x8*>(&As[(wv * 32 + rf * 16 + lr) * LDA + kk + lg * 8]);
#pragma unroll
      for (int f = 0; f < 8; ++f) {
        s16x8 bf = *reinterpret_cast<const s16x8*>(&Bs[(f * 16 + lr) * LDA + kk + lg * 8]);
        acc[0][f] = __builtin_amdgcn_mfma_f32_16x16x32_bf16(af[0], bf, acc[0][f], 0, 0, 0);
        acc[1][f] = __builtin_amdgcn_mfma_f32_16x16x32_bf16(af[1], bf, acc[1][f], 0, 0, 0);
      }
    }
  }

  // ---- h (+eb0) -> As (stride LDH) as bf16; eW1 -> Bs (stride LDH, 64 rows) ----
  __syncthreads();   // stage-1 MFMA reads of As/Bs done
#pragma unroll
  for (int rf = 0; rf < 2; ++rf)
#pragma unroll
    for (int rr = 0; rr < 4; ++rr) {
      int hr = wv * 32 + rf * 16 + lg * 4 + rr;
#pragma unroll
      for (int f = 0; f < 8; ++f) {
        int col = f * 16 + lr;
        As[hr * LDH + col] = f2b(acc[rf][f][rr] + eb0[col]);
      }
    }
  {
    int bn2 = t & 63, bko2 = (t >> 6) * 32;
    const u16* bp = eW1t + (size_t)bn2 * 128 + bko2;
#pragma unroll
    for (int j = 0; j < 4; ++j)
      *reinterpret_cast<uint4*>(&Bs[bn2 * LDH + bko2 + j * 8]) =
          *reinterpret_cast<const uint4*>(bp + j * 8);
  }
  __syncthreads();

  // ---- stage 2: ea = h @ eW1 ----
  f32x4 acc2[2][4];
#pragma unroll
  for (int a = 0; a < 2; ++a)
#pragma unroll
    for (int b = 0; b < 4; ++b) acc2[a][b] = (f32x4){0.f, 0.f, 0.f, 0.f};

#pragma unroll
  for (int kk = 0; kk < 128; kk += 32) {
    s16x8 af[2];
#pragma unroll
    for (int rf = 0; rf < 2; ++rf)
      af[rf] = *reinterpret_cast<const s16x8*>(&As[(wv * 32 + rf * 16 + lr) * LDH + kk + lg * 8]);
#pragma unroll
    for (int f = 0; f < 4; ++f) {
      s16x8 bf = *reinterpret_cast<const s16x8*>(&Bs[(f * 16 + lr) * LDH + kk + lg * 8]);
      acc2[0][f] = __builtin_amdgcn_mfma_f32_16x16x32_bf16(af[0], bf, acc2[0][f], 0, 0, 0);
      acc2[1][f] = __builtin_amdgcn_mfma_f32_16x16x32_bf16(af[1], bf, acc2[1][f], 0, 0, 0);
    }
  }

#pragma unroll
  for (int rf = 0; rf < 2; ++rf)
#pragma unroll
    for (int rr = 0; rr < 4; ++rr) {
      int grow = bm0 + wv * 32 + rf * 16 + lg * 4 + rr;
#pragma unroll
      for (int f = 0; f < 4; ++f) {
        int col = f * 16 + lr;
        eab[(size_t)grow * 64 + col] = f2b(acc2[rf][f][rr] + eb1[col]);
      }
    }
}

// ---------------- node GEMM: C[M,BN] = concat(segs)[M,K] @ Wt^T + bscale*bias ----------------
// EPI 0: store bf16; EPI 1: store f32 + bf16
template<int BN, int EPI>
__global__ __launch_bounds__(256)
void gemm_node(const u16* __restrict__ Wt, const float* __restrict__ bias,
               const float* __restrict__ bscale,
               Seg s0, Seg s1, int M, int K,
               float* __restrict__ outf, u16* __restrict__ outb)
{
  constexpr int BM = 128;
  constexpr int LDA = 72;
  __shared__ u16 As[BM * LDA];
  __shared__ u16 Bs[BN * LDA];

  const int t = threadIdx.x;
  const int wv = t >> 6, lane = t & 63, lr = lane & 15, lg = lane >> 4;
  const int bm0 = blockIdx.x * BM;

  f32x4 acc[2][BN / 16];
#pragma unroll
  for (int a = 0; a < 2; ++a)
#pragma unroll
    for (int b = 0; b < BN / 16; ++b) acc[a][b] = (f32x4){0.f, 0.f, 0.f, 0.f};

  const int ar = t & 127;
  const int ako = (t >> 7) * 32;
  int agrow = bm0 + ar;
  if (agrow >= M) agrow = M - 1;

  constexpr int BPT = (BN * 64) / 256;
  const int bn = (BN == 128) ? (t & 127) : (t & 63);
  const int bko = (BN == 128) ? ((t >> 7) * 32) : ((t >> 6) * 16);

  for (int k0 = 0; k0 < K; k0 += 64) {
    const Seg* sg; int segk;
    if (k0 < s0.width) { sg = &s0; segk = k0; }
    else { sg = &s1; segk = k0 - s0.width; }

    const u16* ap = sg->src + (size_t)agrow * sg->width + segk + ako;
    uint4 av[4];
#pragma unroll
    for (int j = 0; j < 4; ++j) av[j] = *reinterpret_cast<const uint4*>(ap + j * 8);

    const u16* bp = Wt + (size_t)bn * K + k0 + bko;
    uint4 bv[BPT / 8];
#pragma unroll
    for (int j = 0; j < BPT / 8; ++j) bv[j] = *reinterpret_cast<const uint4*>(bp + j * 8);

    __syncthreads();
#pragma unroll
    for (int j = 0; j < 4; ++j)
      *reinterpret_cast<uint4*>(&As[ar * LDA + ako + j * 8]) = av[j];
#pragma unroll
    for (int j = 0; j < BPT / 8; ++j)
      *reinterpret_cast<uint4*>(&Bs[bn * LDA + bko + j * 8]) = bv[j];
    __syncthreads();

#pragma unroll
    for (int kk = 0; kk < 64; kk += 32) {
      s16x8 af[2];
#pragma unroll
      for (int rf = 0; rf < 2; ++rf)
        af[rf] = *reinterpret_cast<const s16x8*>(&As[(wv * 32 + rf * 16 + lr) * LDA + kk + lg * 8]);
#pragma unroll
      for (int f = 0; f < BN / 16; ++f) {
        s16x8 bf = *reinterpret_cast<const s16x8*>(&Bs[(f * 16 + lr) * LDA + kk + lg * 8]);
        acc[0][f] = __builtin_amdgcn_mfma_f32_16x16x32_bf16(af[0], bf, acc[0][f], 0, 0, 0);
        acc[1][f] = __builtin_amdgcn_mfma_f32_16x16x32_bf16(af[1], bf, acc[1][f], 0, 0, 0);
      }
    }
  }

  float bvz[BN / 16];
#pragma unroll
  for (int f = 0; f < BN / 16; ++f) bvz[f] = bias[f * 16 + lr];

#pragma unroll
  for (int rf = 0; rf < 2; ++rf)
#pragma unroll
    for (int rr = 0; rr < 4; ++rr) {
      int grow = bm0 + wv * 32 + rf * 16 + lg * 4 + rr;
      if (grow >= M) continue;
      float bs = bscale ? bscale[grow] : 1.f;
#pragma unroll
      for (int f = 0; f < BN / 16; ++f) {
        float v = acc[rf][f][rr] + bs * bvz[f];
        int col = f * 16 + lr;
        if (EPI == 0) {
          outb[(size_t)grow * BN + col] = f2b(v);
        } else {
          outf[(size_t)grow * BN + col] = v;
          outb[(size_t)grow * BN + col] = f2b(v);
        }
      }
    }
}

// ---------------- sorted-batch pooling: dst[batch[n]][c] += src[n][c] ----------------
__global__ void k_pool(const float* __restrict__ src, const int* __restrict__ batch,
                       float* __restrict__ dst, int n) {
  int c = threadIdx.x;
  int n0 = blockIdx.x * 128;
  if (n0 >= n) return;
  int n1 = n0 + 128; if (n1 > n) n1 = n;
  float acc = 0.f;
  int cur = batch[n0];
  for (int i = n0; i < n1; ++i) {
    int bi = batch[i];
    if (bi != cur) { atomicAdd(&dst[cur * 128 + c], acc); acc = 0.f; cur = bi; }
    acc += src[(size_t)i * 128 + c];
  }
  atomicAdd(&dst[cur * 128 + c], acc);
}

// ---------------- tiny fp32 GEMM ----------------
__global__ void k_small(const float* __restrict__ A0, int w0,
                        const float* __restrict__ A1, int w1,
                        const float* __restrict__ W, const float* __restrict__ b,
                        float* __restrict__ out, int N, int K) {
  int r = blockIdx.x, c = threadIdx.x;
  if (c >= N) return;
  float acc = b[c];
  for (int k = 0; k < K; ++k) {
    float a = (k < w0) ? A0[r * w0 + k] : A1[r * w1 + (k - w0)];
    acc = fmaf(a, W[(size_t)k * N + c], acc);
  }
  out[(size_t)r * N + c] = acc;
}

extern "C" void kernel_launch(void* const* d_in, const int* in_sizes, int n_in,
                              void* d_out, int out_size, void* d_ws, size_t ws_size,
                              hipStream_t stream) {
  const float* x     = (const float*)d_in[0];
  const int*   eidx  = (const int*)d_in[1];
  const float* eattr = (const float*)d_in[2];
  const int*   batch = (const int*)d_in[3];
  const float* eW0 = (const float*)d_in[4];  const float* eb0 = (const float*)d_in[5];
  const float* eW1 = (const float*)d_in[6];  const float* eb1 = (const float*)d_in[7];
  const float* n1W0 = (const float*)d_in[8]; const float* n1b0 = (const float*)d_in[9];
  const float* n1W1 = (const float*)d_in[10];const float* n1b1 = (const float*)d_in[11];
  const float* n2W0 = (const float*)d_in[12];const float* n2b0 = (const float*)d_in[13];
  const float* n2W1 = (const float*)d_in[14];const float* n2b1 = (const float*)d_in[15];
  const float* g1W0 = (const float*)d_in[16];const float* g1b0 = (const float*)d_in[17];
  const float* g1W1 = (const float*)d_in[18];const float* g1b1 = (const float*)d_in[19];
  const float* g2W0 = (const float*)d_in[20];const float* g2b0 = (const float*)d_in[21];
  const float* g2W1 = (const float*)d_in[22];const float* g2b1 = (const float*)d_in[23];
  const float* fW0 = (const float*)d_in[24]; const float* fb0 = (const float*)d_in[25];
  const float* fW1 = (const float*)d_in[26]; const float* fb1 = (const float*)d_in[27];

  const int* rowv = eidx;
  const int* colv = eidx + N_EDGES;

  char* ws = (char*)d_ws;
  size_t off = 0;
  auto alloc = [&](size_t bytes) -> void* {
    void* p = ws + off; off = (off + bytes + 255) & ~(size_t)255; return p;
  };
  u16*   x_b    = (u16*)alloc((size_t)N_NODES * 128 * 2);
  u16*   ea_b   = (u16*)alloc((size_t)N_EDGES * 64 * 2);
  float* x_f    = (float*)alloc((size_t)N_NODES * 128 * 4);
  u16*   hn_b   = (u16*)alloc((size_t)N_NODES * 128 * 2);
  u16*   adjX_b = (u16*)alloc((size_t)N_NODES * 128 * 2);
  u16*   aggE_b = (u16*)alloc((size_t)N_NODES * 64 * 2);
  u16*   agg_b  = (u16*)alloc((size_t)N_NODES * 128 * 2);
  float* gagg_f = (float*)alloc((size_t)N_NODES * 128 * 4);
  float* degf   = (float*)alloc((size_t)N_NODES * 4);
  int*   rowptr = (int*)alloc((size_t)(N_NODES + 1) * 4);
  int*   cursor = (int*)alloc((size_t)N_NODES * 4);
  int*   crow   = (int*)alloc((size_t)N_EDGES * 4);
  int*   ceid   = (int*)alloc((size_t)N_EDGES * 4);
  u16*   wt     = (u16*)alloc((size_t)180224 * 2);
  float* npool  = (float*)alloc((size_t)NB * 128 * 4);
  float* mpool  = (float*)alloc((size_t)NB * 128 * 4);
  float* su0    = (float*)alloc((size_t)NB * 128 * 4);
  float* su1    = (float*)alloc((size_t)NB * 128 * 4);
  float* su2    = (float*)alloc((size_t)NB * 256 * 4);
  (void)ws_size; (void)in_sizes; (void)n_in; (void)out_size;

  u16* eW0t  = wt + 0;       // 128 x 320
  u16* eW1t  = wt + 40960;   // 64  x 128
  u16* n1W0t = wt + 49152;   // 128 x 192
  u16* n1W1t = wt + 73728;   // 128 x 128
  u16* n2W0t = wt + 90112;   // 128 x 256
  u16* n2W1t = wt + 122880;  // 128 x 128
  u16* g1W0t = wt + 139264;  // 128 x 192
  u16* g1W1t = wt + 163840;  // 128 x 128

  // conversions
  k_f2b<<<(N_NODES * 128 + 255) / 256, 256, 0, stream>>>(x, x_b, N_NODES * 128);
  k_f2b<<<(N_EDGES * 64 + 255) / 256, 256, 0, stream>>>(eattr, ea_b, N_EDGES * 64);
  k_wt<<<(320 * 128 + 255) / 256, 256, 0, stream>>>(eW0, eW0t, 320, 128);
  k_wt<<<(128 * 64 + 255) / 256, 256, 0, stream>>>(eW1, eW1t, 128, 64);
  k_wt<<<(192 * 128 + 255) / 256, 256, 0, stream>>>(n1W0, n1W0t, 192, 128);
  k_wt<<<(128 * 128 + 255) / 256, 256, 0, stream>>>(n1W1, n1W1t, 128, 128);
  k_wt<<<(256 * 128 + 255) / 256, 256, 0, stream>>>(n2W0, n2W0t, 256, 128);
  k_wt<<<(128 * 128 + 255) / 256, 256, 0, stream>>>(n2W1, n2W1t, 128, 128);
  k_wt<<<(192 * 128 + 255) / 256, 256, 0, stream>>>(g1W0, g1W0t, 192, 128);
  k_wt<<<(128 * 128 + 255) / 256, 256, 0, stream>>>(g1W1, g1W1t, 128, 128);

  // CSR over col (edge_index constant across MP iterations)
  hipMemsetAsync(cursor, 0, (size_t)N_NODES * 4, stream);
  k_hist<<<(N_EDGES + 255) / 256, 256, 0, stream>>>(colv, cursor);
  k_scan<<<1, 1024, 0, stream>>>(cursor, rowptr, N_NODES);
  hipMemcpyAsync(cursor, rowptr, (size_t)N_NODES * 4, hipMemcpyDeviceToDevice, stream);
  k_fill<<<(N_EDGES + 255) / 256, 256, 0, stream>>>(rowv, colv, cursor, crow, ceid);
  k_deg<<<(N_NODES + 255) / 256, 256, 0, stream>>>(rowptr, degf);

  const int GE = N_EDGES / 128;            // 3125
  const int GN = (N_NODES + 127) / 128;    // 391
  Seg zs{nullptr, 0};

  for (int it = 0; it < 2; ++it) {
    // EdgeModel (fused 2-layer, in-place ea update)
    k_edge<<<GE, 256, 0, stream>>>(x_b, ea_b, rowv, colv, eW0t, eb0, eW1t, eb1);
    // segment sums: adjX (current x), aggE (new ea)
    k_agg<true, true><<<1024, 256, 0, stream>>>(x_b, ea_b, rowptr, crow, ceid, adjX_b, aggE_b);
    // agg = (cat(adjX,aggE)@n1W0 + deg*n1b0)@n1W1 + deg*n1b1
    gemm_node<128, 0><<<GN, 256, 0, stream>>>(n1W0t, n1b0, degf,
        Seg{adjX_b, 128}, Seg{aggE_b, 64}, N_NODES, 192, nullptr, hn_b);
    gemm_node<128, 0><<<GN, 256, 0, stream>>>(n1W1t, n1b1, degf,
        Seg{hn_b, 128}, zs, N_NODES, 128, nullptr, agg_b);
    // x = (cat(x,agg)@n2W0 + n2b0)@n2W1 + n2b1
    gemm_node<128, 0><<<GN, 256, 0, stream>>>(n2W0t, n2b0, nullptr,
        Seg{x_b, 128}, Seg{agg_b, 128}, N_NODES, 256, nullptr, hn_b);
    gemm_node<128, 1><<<GN, 256, 0, stream>>>(n2W1t, n2b1, nullptr,
        Seg{hn_b, 128}, zs, N_NODES, 128, x_f, x_b);
  }

  // GlobalModel (last iteration only): adjX with NEW x, same aggE
  k_agg<true, false><<<1024, 256, 0, stream>>>(x_b, nullptr, rowptr, crow, ceid, adjX_b, nullptr);
  gemm_node<128, 0><<<GN, 256, 0, stream>>>(g1W0t, g1b0, degf,
      Seg{adjX_b, 128}, Seg{aggE_b, 64}, N_NODES, 192, nullptr, hn_b);
  gemm_node<128, 1><<<GN, 256, 0, stream>>>(g1W1t, g1b1, degf,
      Seg{hn_b, 128}, zs, N_NODES, 128, gagg_f, agg_b);

  // pools (batch sorted)
  hipMemsetAsync(npool, 0, (size_t)NB * 128 * 4, stream);
  hipMemsetAsync(mpool, 0, (size_t)NB * 128 * 4, stream);
  k_pool<<<GN, 128, 0, stream>>>(x_f, batch, npool, N_NODES);
  k_pool<<<GN, 128, 0, stream>>>(gagg_f, batch, mpool, N_NODES);

  // global + final MLPs (tiny, fp32)
  k_small<<<NB, 128, 0, stream>>>(npool, 128, mpool, 128, g2W0, g2b0, su0, 128, 256);
  k_small<<<NB, 128, 0, stream>>>(su0, 128, nullptr, 0, g2W1, g2b1, su1, 128, 128);
  k_small<<<NB, 256, 0, stream>>>(su1, 128, nullptr, 0, fW0, fb0, su2, 256, 128);
  k_small<<<NB, 64, 0, stream>>>(su2, 256, nullptr, 0, fW1, fb1, (float*)d_out, 1, 256);
}

// Round 5
// 1028.474 us; speedup vs baseline: 1.9265x; 1.2882x over previous
//
#include <hip/hip_runtime.h>
#include <hip/hip_bf16.h>

#define N_NODES 50000
#define N_EDGES 400000
#define NB 64

typedef unsigned short u16;
typedef unsigned int u32;
typedef __attribute__((ext_vector_type(8))) short s16x8;
typedef __attribute__((ext_vector_type(4))) float f32x4;

__device__ __forceinline__ u16 f2b(float f) {
  __hip_bfloat16 h = __float2bfloat16(f);
  return *reinterpret_cast<const u16*>(&h);
}
__device__ __forceinline__ float b2f(u16 u) {
  u32 v = ((u32)u) << 16;
  return *reinterpret_cast<const float*>(&v);
}

// ---------------- elementwise f32 -> bf16 ----------------
__global__ void k_f2b(const float* __restrict__ in, u16* __restrict__ out, int n) {
  int i = blockIdx.x * 256 + threadIdx.x;
  if (i < n) out[i] = f2b(in[i]);
}

// ---------------- small f32 matmul: C[i][n] = sum_k A[(r0+i)*lda+k]*B[k*ldb+n] (+add) ----------------
// grid = K1 (rows of C), block = N
__global__ void k_mm(const float* __restrict__ A, int lda, int r0,
                     const float* __restrict__ B, int ldb,
                     const float* __restrict__ add, float* __restrict__ C,
                     int K2, int N) {
  int i = blockIdx.x, n = threadIdx.x;
  float acc = add ? add[(size_t)i * N + n] : 0.f;
  for (int k = 0; k < K2; ++k)
    acc = fmaf(A[(size_t)(r0 + i) * lda + k], B[(size_t)k * ldb + n], acc);
  C[(size_t)i * N + n] = acc;
}

// ---------------- pack composed weights (bf16, N-major rows of K) ----------------
// BigWt[n*448+k]: k 0-127 x: [N2a | 0]; 128-255 adjX: [WadjX | A1];
//                 256-319 aggE: [WaggE | C1]; 320-447 degx: [Wdegx | B1]
__global__ void k_pack_iter(const float* __restrict__ N2a, const float* __restrict__ WadjX,
                            const float* __restrict__ A1, const float* __restrict__ WaggE,
                            const float* __restrict__ C1, const float* __restrict__ Wdegx,
                            const float* __restrict__ B1, u16* __restrict__ Wt) {
  int i = blockIdx.x * 256 + threadIdx.x;
  if (i >= 192 * 448) return;
  int n = i / 448, k = i % 448;
  float v;
  if (k < 128)      v = (n < 128) ? N2a[(size_t)k * 128 + n] : 0.f;
  else if (k < 256) { int kk = k - 128; v = (n < 128) ? WadjX[(size_t)kk * 128 + n] : A1[(size_t)kk * 64 + (n - 128)]; }
  else if (k < 320) { int kk = k - 256; v = (n < 128) ? WaggE[(size_t)kk * 128 + n] : C1[(size_t)kk * 64 + (n - 128)]; }
  else              { int kk = k - 320; v = (n < 128) ? Wdegx[(size_t)kk * 128 + n] : B1[(size_t)kk * 64 + (n - 128)]; }
  Wt[(size_t)n * 448 + k] = f2b(v);
}

__global__ void k_pack_gagg(const float* __restrict__ G1a, const float* __restrict__ G1b,
                            u16* __restrict__ Wt) {
  int i = blockIdx.x * 256 + threadIdx.x;
  if (i >= 128 * 192) return;
  int n = i / 192, k = i % 192;
  float v = (k < 128) ? G1a[(size_t)k * 128 + n] : G1b[(size_t)(k - 128) * 128 + n];
  Wt[(size_t)n * 192 + k] = f2b(v);
}

__global__ void k_packbias(const float* __restrict__ d2, const float* __restrict__ ddeg,
                           const float* __restrict__ c0, float* __restrict__ bc,
                           float* __restrict__ bd) {
  int t = threadIdx.x;
  if (t >= 192) return;
  bc[t] = (t < 128) ? d2[t] : 0.f;
  bd[t] = (t < 128) ? ddeg[t] : c0[t - 128];
}

// ---------------- CSR build over col ----------------
__global__ void k_hist(const int* __restrict__ colv, int* __restrict__ deg) {
  int i = blockIdx.x * 256 + threadIdx.x;
  if (i < N_EDGES) atomicAdd(&deg[colv[i]], 1);
}

__global__ void k_scan(const int* __restrict__ deg, int* __restrict__ rowptr, int n) {
  __shared__ int part[1024];
  int t = threadIdx.x;
  int chunk = (n + 1023) / 1024;
  int lo = t * chunk, hi = lo + chunk; if (hi > n) hi = n;
  if (lo > n) lo = n;
  int s = 0;
  for (int i = lo; i < hi; ++i) s += deg[i];
  part[t] = s;
  __syncthreads();
  for (int d = 1; d < 1024; d <<= 1) {
    int v = (t >= d) ? part[t - d] : 0;
    __syncthreads();
    part[t] += v;
    __syncthreads();
  }
  int base = (t == 0) ? 0 : part[t - 1];
  for (int i = lo; i < hi; ++i) { rowptr[i] = base; base += deg[i]; }
  if (t == 1023) rowptr[n] = part[1023];
}

__global__ void k_fill(const int* __restrict__ rowv, const int* __restrict__ colv,
                       int* __restrict__ cursor, int* __restrict__ crow, int* __restrict__ ceid) {
  int i = blockIdx.x * 256 + threadIdx.x;
  if (i >= N_EDGES) return;
  int pos = atomicAdd(&cursor[colv[i]], 1);
  crow[pos] = rowv[i];
  ceid[pos] = i;
}

__global__ void k_deg(const int* __restrict__ rowptr, float* __restrict__ degf) {
  int i = blockIdx.x * 256 + threadIdx.x;
  if (i < N_NODES) degf[i] = (float)(rowptr[i + 1] - rowptr[i]);
}

// ---------------- CSR gather segment-sums: adjX[v]=sum x[crow], aggE0[v]=sum edge_attr ----------------
template<bool DOE>
__global__ void k_agg(const u16* __restrict__ xb, const float* __restrict__ eaf,
                      const int* __restrict__ rowptr, const int* __restrict__ crow,
                      const int* __restrict__ ceid,
                      u16* __restrict__ outX, u16* __restrict__ outE) {
  int wpb = blockDim.x >> 6;
  int w = blockIdx.x * wpb + (threadIdx.x >> 6);
  int l = threadIdx.x & 63;
  int nw = gridDim.x * wpb;
  for (int v = w; v < N_NODES; v += nw) {
    int s = rowptr[v], e1 = rowptr[v + 1];
    float ax0 = 0.f, ax1 = 0.f, ae = 0.f;
    int i = s;
    for (; i + 1 < e1; i += 2) {
      int r0 = crow[i], r1 = crow[i + 1];
      u32 a = *reinterpret_cast<const u32*>(&xb[(size_t)r0 * 128 + l * 2]);
      u32 b = *reinterpret_cast<const u32*>(&xb[(size_t)r1 * 128 + l * 2]);
      ax0 += b2f((u16)(a & 0xffff)) + b2f((u16)(b & 0xffff));
      ax1 += b2f((u16)(a >> 16)) + b2f((u16)(b >> 16));
      if (DOE) ae += eaf[(size_t)ceid[i] * 64 + l] + eaf[(size_t)ceid[i + 1] * 64 + l];
    }
    if (i < e1) {
      u32 a = *reinterpret_cast<const u32*>(&xb[(size_t)crow[i] * 128 + l * 2]);
      ax0 += b2f((u16)(a & 0xffff));
      ax1 += b2f((u16)(a >> 16));
      if (DOE) ae += eaf[(size_t)ceid[i] * 64 + l];
    }
    u32 pk = ((u32)f2b(ax1) << 16) | (u32)f2b(ax0);
    *reinterpret_cast<u32*>(&outX[(size_t)v * 128 + l * 2]) = pk;
    if (DOE) outE[(size_t)v * 64 + l] = f2b(ae);
  }
}

// ---------------- fused node GEMM over concatenated K-chunks of 64 ----------------
// C[M,BN] = cat(chunks)[M, NCH*64] @ Wt^T + bc + deg*bd
// col < SPLIT: write outb0 (bf16, width SPLIT) and/or outf0 (f32);
// col >= SPLIT: write outb1 (bf16, width BN-SPLIT)
struct Chunks { const u16* src[7]; int width[7]; int koff[7]; int scl[7]; };

template<int BN, int NCH>
__global__ __launch_bounds__(256)
void gemm_fused(const u16* __restrict__ Wt, int KTOT,
                const float* __restrict__ bc, const float* __restrict__ bd,
                const float* __restrict__ degf, Chunks ch, int M, int SPLIT,
                u16* __restrict__ outb0, float* __restrict__ outf0, u16* __restrict__ outb1)
{
  constexpr int LDA = 72;
  constexpr int BP = BN / 64;          // B-staging passes (4 threads/row x 16 elems, 64 rows/pass)
  __shared__ u16 As[128 * LDA];
  __shared__ u16 Bs[BN * LDA];

  const int t = threadIdx.x;
  const int wv = t >> 6, lane = t & 63, lr = lane & 15, lg = lane >> 4;
  const int bm0 = blockIdx.x * 128;

  f32x4 acc[2][BN / 16];
#pragma unroll
  for (int a = 0; a < 2; ++a)
#pragma unroll
    for (int b = 0; b < BN / 16; ++b) acc[a][b] = (f32x4){0.f, 0.f, 0.f, 0.f};

  const int ar = t & 127;
  const int ako = (t >> 7) * 32;
  int agrow = bm0 + ar;
  if (agrow >= M) agrow = M - 1;
  const float dg_a = degf[agrow];

  const int br0 = t >> 2;              // B row within a pass (0..63)
  const int bo  = (t & 3) * 16;        // B k-offset (0,16,32,48)

#pragma unroll
  for (int c = 0; c < NCH; ++c) {
    const u16* ap = ch.src[c] + (size_t)agrow * ch.width[c] + ch.koff[c] + ako;
    uint4 av[4];
#pragma unroll
    for (int j = 0; j < 4; ++j) av[j] = *reinterpret_cast<const uint4*>(ap + j * 8);
    if (ch.scl[c]) {
#pragma unroll
      for (int j = 0; j < 4; ++j) {
        u32* p = reinterpret_cast<u32*>(&av[j]);
#pragma unroll
        for (int q = 0; q < 4; ++q) {
          u32 w = p[q];
          float lo = b2f((u16)(w & 0xffff)) * dg_a;
          float hi = b2f((u16)(w >> 16)) * dg_a;
          p[q] = ((u32)f2b(hi) << 16) | (u32)f2b(lo);
        }
      }
    }
    uint4 bv[BP * 2];
#pragma unroll
    for (int p = 0; p < BP; ++p) {
      const u16* bp = Wt + (size_t)(p * 64 + br0) * KTOT + c * 64 + bo;
      bv[p * 2]     = *reinterpret_cast<const uint4*>(bp);
      bv[p * 2 + 1] = *reinterpret_cast<const uint4*>(bp + 8);
    }
    __syncthreads();   // previous chunk's MFMA reads done before overwrite
#pragma unroll
    for (int j = 0; j < 4; ++j)
      *reinterpret_cast<uint4*>(&As[ar * LDA + ako + j * 8]) = av[j];
#pragma unroll
    for (int p = 0; p < BP; ++p) {
      *reinterpret_cast<uint4*>(&Bs[(p * 64 + br0) * LDA + bo])     = bv[p * 2];
      *reinterpret_cast<uint4*>(&Bs[(p * 64 + br0) * LDA + bo + 8]) = bv[p * 2 + 1];
    }
    __syncthreads();   // tiles visible

#pragma unroll
    for (int kk = 0; kk < 64; kk += 32) {
      s16x8 af[2];
#pragma unroll
      for (int rf = 0; rf < 2; ++rf)
        af[rf] = *reinterpret_cast<const s16x8*>(&As[(wv * 32 + rf * 16 + lr) * LDA + kk + lg * 8]);
#pragma unroll
      for (int f = 0; f < BN / 16; ++f) {
        s16x8 bf = *reinterpret_cast<const s16x8*>(&Bs[(f * 16 + lr) * LDA + kk + lg * 8]);
        acc[0][f] = __builtin_amdgcn_mfma_f32_16x16x32_bf16(af[0], bf, acc[0][f], 0, 0, 0);
        acc[1][f] = __builtin_amdgcn_mfma_f32_16x16x32_bf16(af[1], bf, acc[1][f], 0, 0, 0);
      }
    }
  }

  float bcv[BN / 16], bdv[BN / 16];
#pragma unroll
  for (int f = 0; f < BN / 16; ++f) {
    int col = f * 16 + lr;
    bcv[f] = bc ? bc[col] : 0.f;
    bdv[f] = bd ? bd[col] : 0.f;
  }

#pragma unroll
  for (int rf = 0; rf < 2; ++rf)
#pragma unroll
    for (int rr = 0; rr < 4; ++rr) {
      int grow = bm0 + wv * 32 + rf * 16 + lg * 4 + rr;
      if (grow >= M) continue;
      float dgr = degf[grow];
#pragma unroll
      for (int f = 0; f < BN / 16; ++f) {
        int col = f * 16 + lr;
        float v = acc[rf][f][rr] + bcv[f] + dgr * bdv[f];
        if (col < SPLIT) {
          if (outb0) outb0[(size_t)grow * SPLIT + col] = f2b(v);
          if (outf0) outf0[(size_t)grow * SPLIT + col] = v;
        } else {
          outb1[(size_t)grow * (BN - SPLIT) + (col - SPLIT)] = f2b(v);
        }
      }
    }
}

// ---------------- sorted-batch pooling ----------------
__global__ void k_pool(const float* __restrict__ src, const int* __restrict__ batch,
                       float* __restrict__ dst, int n) {
  int c = threadIdx.x;
  int n0 = blockIdx.x * 128;
  if (n0 >= n) return;
  int n1 = n0 + 128; if (n1 > n) n1 = n;
  float acc = 0.f;
  int cur = batch[n0];
  for (int i = n0; i < n1; ++i) {
    int bi = batch[i];
    if (bi != cur) { atomicAdd(&dst[cur * 128 + c], acc); acc = 0.f; cur = bi; }
    acc += src[(size_t)i * 128 + c];
  }
  atomicAdd(&dst[cur * 128 + c], acc);
}

// ---------------- tiny fp32 GEMM ----------------
__global__ void k_small(const float* __restrict__ A0, int w0,
                        const float* __restrict__ A1, int w1,
                        const float* __restrict__ W, const float* __restrict__ b,
                        float* __restrict__ out, int N, int K) {
  int r = blockIdx.x, c = threadIdx.x;
  if (c >= N) return;
  float acc = b[c];
  for (int k = 0; k < K; ++k) {
    float a = (k < w0) ? A0[r * w0 + k] : A1[r * w1 + (k - w0)];
    acc = fmaf(a, W[(size_t)k * N + c], acc);
  }
  out[(size_t)r * N + c] = acc;
}

extern "C" void kernel_launch(void* const* d_in, const int* in_sizes, int n_in,
                              void* d_out, int out_size, void* d_ws, size_t ws_size,
                              hipStream_t stream) {
  const float* x     = (const float*)d_in[0];
  const int*   eidx  = (const int*)d_in[1];
  const float* eattr = (const float*)d_in[2];
  const int*   batch = (const int*)d_in[3];
  const float* eW0 = (const float*)d_in[4];  const float* eb0 = (const float*)d_in[5];
  const float* eW1 = (const float*)d_in[6];  const float* eb1 = (const float*)d_in[7];
  const float* n1W0 = (const float*)d_in[8]; const float* n1b0 = (const float*)d_in[9];
  const float* n1W1 = (const float*)d_in[10];const float* n1b1 = (const float*)d_in[11];
  const float* n2W0 = (const float*)d_in[12];const float* n2b0 = (const float*)d_in[13];
  const float* n2W1 = (const float*)d_in[14];const float* n2b1 = (const float*)d_in[15];
  const float* g1W0 = (const float*)d_in[16];const float* g1b0 = (const float*)d_in[17];
  const float* g1W1 = (const float*)d_in[18];const float* g1b1 = (const float*)d_in[19];
  const float* g2W0 = (const float*)d_in[20];const float* g2b0 = (const float*)d_in[21];
  const float* g2W1 = (const float*)d_in[22];const float* g2b1 = (const float*)d_in[23];
  const float* fW0 = (const float*)d_in[24]; const float* fb0 = (const float*)d_in[25];
  const float* fW1 = (const float*)d_in[26]; const float* fb1 = (const float*)d_in[27];

  const int* rowv = eidx;
  const int* colv = eidx + N_EDGES;

  char* ws = (char*)d_ws;
  size_t off = 0;
  auto alloc = [&](size_t bytes) -> void* {
    void* p = ws + off; off = (off + bytes + 255) & ~(size_t)255; return p;
  };
  u16*   x_b    = (u16*)alloc((size_t)N_NODES * 128 * 2);
  float* x_f    = (float*)alloc((size_t)N_NODES * 128 * 4);
  u16*   adjX_b = (u16*)alloc((size_t)N_NODES * 128 * 2);
  u16*   aggE_b = (u16*)alloc((size_t)N_NODES * 64 * 2);
  float* gagg_f = (float*)alloc((size_t)N_NODES * 128 * 4);
  float* degf   = (float*)alloc((size_t)N_NODES * 4);
  int*   rowptr = (int*)alloc((size_t)(N_NODES + 1) * 4);
  int*   cursor = (int*)alloc((size_t)N_NODES * 4);
  int*   crow   = (int*)alloc((size_t)N_EDGES * 4);
  int*   ceid   = (int*)alloc((size_t)N_EDGES * 4);
  // f32 weight-composition scratch
  float* N1a   = (float*)alloc(128 * 128 * 4);
  float* N1b   = (float*)alloc(64 * 128 * 4);
  float* N2a   = (float*)alloc(128 * 128 * 4);
  float* N2b   = (float*)alloc(128 * 128 * 4);
  float* A1    = (float*)alloc(128 * 64 * 4);
  float* B1    = (float*)alloc(128 * 64 * 4);
  float* C1    = (float*)alloc(64 * 64 * 4);
  float* G1a   = (float*)alloc(128 * 128 * 4);
  float* G1b   = (float*)alloc(64 * 128 * 4);
  float* T1    = (float*)alloc(64 * 128 * 4);
  float* U1    = (float*)alloc(128 * 128 * 4);
  float* WadjX = (float*)alloc(128 * 128 * 4);
  float* WaggE = (float*)alloc(64 * 128 * 4);
  float* Wdegx = (float*)alloc(128 * 128 * 4);
  float* c0    = (float*)alloc(64 * 4);
  float* d1    = (float*)alloc(128 * 4);
  float* d2    = (float*)alloc(128 * 4);
  float* tmpv  = (float*)alloc(128 * 4);
  float* ddeg  = (float*)alloc(128 * 4);
  float* e1    = (float*)alloc(128 * 4);
  float* bc    = (float*)alloc(192 * 4);
  float* bd    = (float*)alloc(192 * 4);
  u16*   BigWt  = (u16*)alloc((size_t)192 * 448 * 2);
  u16*   GaggWt = (u16*)alloc((size_t)128 * 192 * 2);
  float* npool  = (float*)alloc((size_t)NB * 128 * 4);
  float* mpool  = (float*)alloc((size_t)NB * 128 * 4);
  float* su0    = (float*)alloc((size_t)NB * 128 * 4);
  float* su1    = (float*)alloc((size_t)NB * 128 * 4);
  float* su2    = (float*)alloc((size_t)NB * 256 * 4);
  (void)ws_size; (void)in_sizes; (void)n_in; (void)out_size;

  // x -> bf16
  k_f2b<<<(N_NODES * 128 + 255) / 256, 256, 0, stream>>>(x, x_b, N_NODES * 128);

  // ---- weight composition (f32, tiny) ----
  k_mm<<<128, 128, 0, stream>>>(n1W0, 128, 0,   n1W1, 128, nullptr, N1a, 128, 128);
  k_mm<<<64,  128, 0, stream>>>(n1W0, 128, 128, n1W1, 128, nullptr, N1b, 128, 128);
  k_mm<<<128, 128, 0, stream>>>(n2W0, 128, 0,   n2W1, 128, nullptr, N2a, 128, 128);
  k_mm<<<128, 128, 0, stream>>>(n2W0, 128, 128, n2W1, 128, nullptr, N2b, 128, 128);
  k_mm<<<128, 64,  0, stream>>>(eW0, 128, 0,    eW1, 64,  nullptr, A1, 128, 64);
  k_mm<<<128, 64,  0, stream>>>(eW0, 128, 128,  eW1, 64,  nullptr, B1, 128, 64);
  k_mm<<<64,  64,  0, stream>>>(eW0, 128, 256,  eW1, 64,  nullptr, C1, 128, 64);
  k_mm<<<128, 128, 0, stream>>>(g1W0, 128, 0,   g1W1, 128, nullptr, G1a, 128, 128);
  k_mm<<<64,  128, 0, stream>>>(g1W0, 128, 128, g1W1, 128, nullptr, G1b, 128, 128);
  k_mm<<<64,  128, 0, stream>>>(N1b, 128, 0, N2b, 128, nullptr, T1, 128, 128);
  k_mm<<<128, 128, 0, stream>>>(N1a, 128, 0, N2b, 128, nullptr, U1, 128, 128);
  k_mm<<<128, 128, 0, stream>>>(A1, 64, 0, T1, 128, U1, WadjX, 64, 128);
  k_mm<<<64,  128, 0, stream>>>(C1, 64, 0, T1, 128, nullptr, WaggE, 64, 128);
  k_mm<<<128, 128, 0, stream>>>(B1, 64, 0, T1, 128, nullptr, Wdegx, 64, 128);
  k_mm<<<1, 64,  0, stream>>>(eb0, 128, 0, eW1, 64, eb1, c0, 128, 64);
  k_mm<<<1, 128, 0, stream>>>(n1b0, 128, 0, n1W1, 128, n1b1, d1, 128, 128);
  k_mm<<<1, 128, 0, stream>>>(n2b0, 128, 0, n2W1, 128, n2b1, d2, 128, 128);
  k_mm<<<1, 128, 0, stream>>>(c0, 64, 0, T1, 128, nullptr, tmpv, 64, 128);
  k_mm<<<1, 128, 0, stream>>>(d1, 128, 0, N2b, 128, tmpv, ddeg, 128, 128);
  k_mm<<<1, 128, 0, stream>>>(g1b0, 128, 0, g1W1, 128, g1b1, e1, 128, 128);
  k_pack_iter<<<(192 * 448 + 255) / 256, 256, 0, stream>>>(N2a, WadjX, A1, WaggE, C1, Wdegx, B1, BigWt);
  k_pack_gagg<<<(128 * 192 + 255) / 256, 256, 0, stream>>>(G1a, G1b, GaggWt);
  k_packbias<<<1, 192, 0, stream>>>(d2, ddeg, c0, bc, bd);

  // ---- CSR over col ----
  hipMemsetAsync(cursor, 0, (size_t)N_NODES * 4, stream);
  k_hist<<<(N_EDGES + 255) / 256, 256, 0, stream>>>(colv, cursor);
  k_scan<<<1, 1024, 0, stream>>>(cursor, rowptr, N_NODES);
  hipMemcpyAsync(cursor, rowptr, (size_t)N_NODES * 4, hipMemcpyDeviceToDevice, stream);
  k_fill<<<(N_EDGES + 255) / 256, 256, 0, stream>>>(rowv, colv, cursor, crow, ceid);
  k_deg<<<(N_NODES + 255) / 256, 256, 0, stream>>>(rowptr, degf);

  const int GN = (N_NODES + 127) / 128;    // 391

  Chunks chIter;
  chIter.src[0] = x_b;    chIter.width[0] = 128; chIter.koff[0] = 0;  chIter.scl[0] = 0;
  chIter.src[1] = x_b;    chIter.width[1] = 128; chIter.koff[1] = 64; chIter.scl[1] = 0;
  chIter.src[2] = adjX_b; chIter.width[2] = 128; chIter.koff[2] = 0;  chIter.scl[2] = 0;
  chIter.src[3] = adjX_b; chIter.width[3] = 128; chIter.koff[3] = 64; chIter.scl[3] = 0;
  chIter.src[4] = aggE_b; chIter.width[4] = 64;  chIter.koff[4] = 0;  chIter.scl[4] = 0;
  chIter.src[5] = x_b;    chIter.width[5] = 128; chIter.koff[5] = 0;  chIter.scl[5] = 1;
  chIter.src[6] = x_b;    chIter.width[6] = 128; chIter.koff[6] = 64; chIter.scl[6] = 1;

  Chunks chG;
  chG.src[0] = adjX_b; chG.width[0] = 128; chG.koff[0] = 0;  chG.scl[0] = 0;
  chG.src[1] = adjX_b; chG.width[1] = 128; chG.koff[1] = 64; chG.scl[1] = 0;
  chG.src[2] = aggE_b; chG.width[2] = 64;  chG.koff[2] = 0;  chG.scl[2] = 0;
  for (int c = 3; c < 7; ++c) { chG.src[c] = aggE_b; chG.width[c] = 64; chG.koff[c] = 0; chG.scl[c] = 0; }

  // ---- iteration 1: adjX(x0) + aggE0; fused update -> x1, aggE1 (in place) ----
  k_agg<true><<<1024, 256, 0, stream>>>(x_b, eattr, rowptr, crow, ceid, adjX_b, aggE_b);
  gemm_fused<192, 7><<<GN, 256, 0, stream>>>(BigWt, 448, bc, bd, degf, chIter, N_NODES, 128,
                                             x_b, nullptr, aggE_b);
  // ---- iteration 2: adjX(x1); fused update -> x2 (bf16+f32), aggE2 ----
  k_agg<false><<<1024, 256, 0, stream>>>(x_b, nullptr, rowptr, crow, ceid, adjX_b, nullptr);
  gemm_fused<192, 7><<<GN, 256, 0, stream>>>(BigWt, 448, bc, bd, degf, chIter, N_NODES, 128,
                                             x_b, x_f, aggE_b);
  // ---- global: adjX(x2); gagg = adjX@G1a + aggE2@G1b + deg*e1 ----
  k_agg<false><<<1024, 256, 0, stream>>>(x_b, nullptr, rowptr, crow, ceid, adjX_b, nullptr);
  gemm_fused<128, 3><<<GN, 256, 0, stream>>>(GaggWt, 192, nullptr, e1, degf, chG, N_NODES, 128,
                                             nullptr, gagg_f, nullptr);

  // ---- pools (batch sorted) ----
  hipMemsetAsync(npool, 0, (size_t)NB * 128 * 4, stream);
  hipMemsetAsync(mpool, 0, (size_t)NB * 128 * 4, stream);
  k_pool<<<GN, 128, 0, stream>>>(x_f, batch, npool, N_NODES);
  k_pool<<<GN, 128, 0, stream>>>(gagg_f, batch, mpool, N_NODES);

  // ---- global + final MLPs (tiny, f32) ----
  k_small<<<NB, 128, 0, stream>>>(npool, 128, mpool, 128, g2W0, g2b0, su0, 128, 256);
  k_small<<<NB, 128, 0, stream>>>(su0, 128, nullptr, 0, g2W1, g2b1, su1, 128, 128);
  k_small<<<NB, 256, 0, stream>>>(su1, 128, nullptr, 0, fW0, fb0, su2, 256, 128);
  k_small<<<NB, 64, 0, stream>>>(su2, 256, nullptr, 0, fW1, fb1, (float*)d_out, 1, 256);
}

// Round 6
// 775.502 us; speedup vs baseline: 2.5550x; 1.3262x over previous
//
#include <hip/hip_runtime.h>
#include <hip/hip_bf16.h>

#define N_NODES 50000
#define N_EDGES 400000
#define NB 64

typedef unsigned short u16;
typedef unsigned int u32;
typedef __attribute__((ext_vector_type(8))) short s16x8;
typedef __attribute__((ext_vector_type(4))) float f32x4;

__device__ __forceinline__ u16 f2b(float f) {
  __hip_bfloat16 h = __float2bfloat16(f);
  return *reinterpret_cast<const u16*>(&h);
}
__device__ __forceinline__ float b2f(u16 u) {
  u32 v = ((u32)u) << 16;
  return *reinterpret_cast<const float*>(&v);
}

// ---------------- elementwise f32 -> bf16 ----------------
__global__ void k_f2b(const float* __restrict__ in, u16* __restrict__ out, int n) {
  int i = blockIdx.x * 256 + threadIdx.x;
  if (i < n) out[i] = f2b(in[i]);
}

// ---------------- batched small f32 matmuls ----------------
struct MMOp { const float* A; const float* B; const float* add; float* C;
              int lda, r0, ldb, K2, N, rows; };
struct MMBatch { MMOp op[13]; };

__global__ void k_mmb(MMBatch mb) {
  MMOp o = mb.op[blockIdx.y];
  int i = blockIdx.x;
  int n = threadIdx.x;
  if (i >= o.rows || n >= o.N) return;
  float acc = o.add ? o.add[(size_t)i * o.N + n] : 0.f;
  for (int k = 0; k < o.K2; ++k)
    acc = fmaf(o.A[(size_t)(o.r0 + i) * o.lda + k], o.B[(size_t)k * o.ldb + n], acc);
  o.C[(size_t)i * o.N + n] = acc;
}

__global__ void k_mm(const float* __restrict__ A, int lda, int r0,
                     const float* __restrict__ B, int ldb,
                     const float* __restrict__ add, float* __restrict__ C,
                     int K2, int N) {
  int i = blockIdx.x, n = threadIdx.x;
  if (n >= N) return;
  float acc = add ? add[(size_t)i * N + n] : 0.f;
  for (int k = 0; k < K2; ++k)
    acc = fmaf(A[(size_t)(r0 + i) * lda + k], B[(size_t)k * ldb + n], acc);
  C[(size_t)i * N + n] = acc;
}

// ---------------- pack composed weights (bf16, N-major rows of K) ----------------
__global__ void k_pack_iter(const float* __restrict__ N2a, const float* __restrict__ WadjX,
                            const float* __restrict__ A1, const float* __restrict__ WaggE,
                            const float* __restrict__ C1, const float* __restrict__ Wdegx,
                            const float* __restrict__ B1, u16* __restrict__ Wt) {
  int i = blockIdx.x * 256 + threadIdx.x;
  if (i >= 192 * 448) return;
  int n = i / 448, k = i % 448;
  float v;
  if (k < 128)      v = (n < 128) ? N2a[(size_t)k * 128 + n] : 0.f;
  else if (k < 256) { int kk = k - 128; v = (n < 128) ? WadjX[(size_t)kk * 128 + n] : A1[(size_t)kk * 64 + (n - 128)]; }
  else if (k < 320) { int kk = k - 256; v = (n < 128) ? WaggE[(size_t)kk * 128 + n] : C1[(size_t)kk * 64 + (n - 128)]; }
  else              { int kk = k - 320; v = (n < 128) ? Wdegx[(size_t)kk * 128 + n] : B1[(size_t)kk * 64 + (n - 128)]; }
  Wt[(size_t)n * 448 + k] = f2b(v);
}

__global__ void k_packbias(const float* __restrict__ d2, const float* __restrict__ ddeg,
                           const float* __restrict__ c0, float* __restrict__ bc,
                           float* __restrict__ bd) {
  int t = threadIdx.x;
  if (t >= 192) return;
  bc[t] = (t < 128) ? d2[t] : 0.f;
  bd[t] = (t < 128) ? ddeg[t] : c0[t - 128];
}

// ---------------- CSR build over col ----------------
__global__ void k_hist(const int* __restrict__ colv, int* __restrict__ deg) {
  int i = blockIdx.x * 256 + threadIdx.x;
  if (i < N_EDGES) atomicAdd(&deg[colv[i]], 1);
}

// deg aliases cursor: read deg[i] then write cursor[i] (same thread, in order)
__global__ void k_scan(const int* __restrict__ deg, int* __restrict__ rowptr,
                       int* __restrict__ cursor, float* __restrict__ degf, int n) {
  __shared__ int part[1024];
  int t = threadIdx.x;
  int chunk = (n + 1023) / 1024;
  int lo = t * chunk, hi = lo + chunk; if (hi > n) hi = n;
  if (lo > n) lo = n;
  int s = 0;
  for (int i = lo; i < hi; ++i) s += deg[i];
  part[t] = s;
  __syncthreads();
  for (int d = 1; d < 1024; d <<= 1) {
    int v = (t >= d) ? part[t - d] : 0;
    __syncthreads();
    part[t] += v;
    __syncthreads();
  }
  int base = (t == 0) ? 0 : part[t - 1];
  for (int i = lo; i < hi; ++i) {
    int d = deg[i];
    rowptr[i] = base;
    cursor[i] = base;
    degf[i] = (float)d;
    base += d;
  }
  if (t == 1023) rowptr[n] = part[1023];
}

__global__ void k_fill(const int* __restrict__ rowv, const int* __restrict__ colv,
                       int* __restrict__ cursor, int* __restrict__ crow, int* __restrict__ ceid) {
  int i = blockIdx.x * 256 + threadIdx.x;
  if (i >= N_EDGES) return;
  int pos = atomicAdd(&cursor[colv[i]], 1);
  crow[pos] = rowv[i];
  ceid[pos] = i;
}

// ---------------- cnt[v][b] = #edges with row=v, batch[col]=b ----------------
__global__ void k_cnt(const int* __restrict__ rowv, const int* __restrict__ colv,
                      const int* __restrict__ batch, float* __restrict__ cnt) {
  int e = blockIdx.x * 256 + threadIdx.x;
  if (e >= N_EDGES) return;
  atomicAdd(&cnt[(size_t)rowv[e] * 64 + batch[colv[e]]], 1.0f);
}

// ---------------- P_adjX[b][c] = sum_v cnt[v][b] * x2[v][c] (streaming weighted pool) ----------------
__global__ __launch_bounds__(256)
void k_cntgemm(const float* __restrict__ cnt, const u16* __restrict__ xb,
               float* __restrict__ P) {
  __shared__ float cs[8][64];
  int t = threadIdx.x, c = t & 127, half = t >> 7;
  float acc[32];
#pragma unroll
  for (int q = 0; q < 32; ++q) acc[q] = 0.f;
  int span = (N_NODES + gridDim.x - 1) / gridDim.x;
  int v0 = blockIdx.x * span;
  int v1 = v0 + span; if (v1 > N_NODES) v1 = N_NODES;
  for (int vt = v0; vt < v1; vt += 8) {
    int nv = v1 - vt; if (nv > 8) nv = 8;
    for (int idx = t; idx < nv * 64; idx += 256)
      cs[idx >> 6][idx & 63] = cnt[(size_t)(vt + (idx >> 6)) * 64 + (idx & 63)];
    __syncthreads();
    for (int j = 0; j < nv; ++j) {
      float xv = b2f(xb[(size_t)(vt + j) * 128 + c]);
#pragma unroll
      for (int q = 0; q < 32; ++q) acc[q] = fmaf(cs[j][half * 32 + q], xv, acc[q]);
    }
    __syncthreads();
  }
#pragma unroll
  for (int q = 0; q < 32; ++q)
    atomicAdd(&P[(size_t)(half * 32 + q) * 128 + c], acc[q]);
}

// ---------------- CSR gather segment-sums (4-way unrolled) ----------------
template<bool DOE>
__global__ void k_agg(const u16* __restrict__ xb, const float* __restrict__ eaf,
                      const int* __restrict__ rowptr, const int* __restrict__ crow,
                      const int* __restrict__ ceid,
                      u16* __restrict__ outX, u16* __restrict__ outE) {
  int wpb = blockDim.x >> 6;
  int w = blockIdx.x * wpb + (threadIdx.x >> 6);
  int l = threadIdx.x & 63;
  int nw = gridDim.x * wpb;
  for (int v = w; v < N_NODES; v += nw) {
    int s = rowptr[v], e1 = rowptr[v + 1];
    float ax0 = 0.f, ax1 = 0.f, ae = 0.f;
    int i = s;
    for (; i + 3 < e1; i += 4) {
      int r0 = crow[i], r1 = crow[i + 1], r2 = crow[i + 2], r3 = crow[i + 3];
      u32 a0 = *reinterpret_cast<const u32*>(&xb[(size_t)r0 * 128 + l * 2]);
      u32 a1 = *reinterpret_cast<const u32*>(&xb[(size_t)r1 * 128 + l * 2]);
      u32 a2 = *reinterpret_cast<const u32*>(&xb[(size_t)r2 * 128 + l * 2]);
      u32 a3 = *reinterpret_cast<const u32*>(&xb[(size_t)r3 * 128 + l * 2]);
      float e0, ev1, ev2, ev3;
      if (DOE) {
        int q0 = ceid[i], q1 = ceid[i + 1], q2 = ceid[i + 2], q3 = ceid[i + 3];
        e0  = eaf[(size_t)q0 * 64 + l];
        ev1 = eaf[(size_t)q1 * 64 + l];
        ev2 = eaf[(size_t)q2 * 64 + l];
        ev3 = eaf[(size_t)q3 * 64 + l];
      }
      ax0 += b2f((u16)(a0 & 0xffff)) + b2f((u16)(a1 & 0xffff))
           + b2f((u16)(a2 & 0xffff)) + b2f((u16)(a3 & 0xffff));
      ax1 += b2f((u16)(a0 >> 16)) + b2f((u16)(a1 >> 16))
           + b2f((u16)(a2 >> 16)) + b2f((u16)(a3 >> 16));
      if (DOE) ae += e0 + ev1 + ev2 + ev3;
    }
    for (; i < e1; ++i) {
      u32 a = *reinterpret_cast<const u32*>(&xb[(size_t)crow[i] * 128 + l * 2]);
      ax0 += b2f((u16)(a & 0xffff));
      ax1 += b2f((u16)(a >> 16));
      if (DOE) ae += eaf[(size_t)ceid[i] * 64 + l];
    }
    u32 pk = ((u32)f2b(ax1) << 16) | (u32)f2b(ax0);
    *reinterpret_cast<u32*>(&outX[(size_t)v * 128 + l * 2]) = pk;
    if (DOE) outE[(size_t)v * 64 + l] = f2b(ae);
  }
}

// ---------------- fused node GEMM over concatenated K-chunks of 64 ----------------
struct Chunks { const u16* src[7]; int width[7]; int koff[7]; int scl[7]; };

template<int BN, int NCH>
__global__ __launch_bounds__(256)
void gemm_fused(const u16* __restrict__ Wt, int KTOT,
                const float* __restrict__ bc, const float* __restrict__ bd,
                const float* __restrict__ degf, Chunks ch, int M, int SPLIT,
                u16* __restrict__ outb0, float* __restrict__ outf0, u16* __restrict__ outb1)
{
  constexpr int LDA = 72;
  constexpr int BP = BN / 64;
  __shared__ u16 As[128 * LDA];
  __shared__ u16 Bs[BN * LDA];

  const int t = threadIdx.x;
  const int wv = t >> 6, lane = t & 63, lr = lane & 15, lg = lane >> 4;
  const int bm0 = blockIdx.x * 128;

  f32x4 acc[2][BN / 16];
#pragma unroll
  for (int a = 0; a < 2; ++a)
#pragma unroll
    for (int b = 0; b < BN / 16; ++b) acc[a][b] = (f32x4){0.f, 0.f, 0.f, 0.f};

  const int ar = t & 127;
  const int ako = (t >> 7) * 32;
  int agrow = bm0 + ar;
  if (agrow >= M) agrow = M - 1;
  const float dg_a = degf[agrow];

  const int br0 = t >> 2;
  const int bo  = (t & 3) * 16;

#pragma unroll
  for (int c = 0; c < NCH; ++c) {
    const u16* ap = ch.src[c] + (size_t)agrow * ch.width[c] + ch.koff[c] + ako;
    uint4 av[4];
#pragma unroll
    for (int j = 0; j < 4; ++j) av[j] = *reinterpret_cast<const uint4*>(ap + j * 8);
    if (ch.scl[c]) {
#pragma unroll
      for (int j = 0; j < 4; ++j) {
        u32* p = reinterpret_cast<u32*>(&av[j]);
#pragma unroll
        for (int q = 0; q < 4; ++q) {
          u32 w = p[q];
          float lo = b2f((u16)(w & 0xffff)) * dg_a;
          float hi = b2f((u16)(w >> 16)) * dg_a;
          p[q] = ((u32)f2b(hi) << 16) | (u32)f2b(lo);
        }
      }
    }
    uint4 bv[BP * 2];
#pragma unroll
    for (int p = 0; p < BP; ++p) {
      const u16* bp = Wt + (size_t)(p * 64 + br0) * KTOT + c * 64 + bo;
      bv[p * 2]     = *reinterpret_cast<const uint4*>(bp);
      bv[p * 2 + 1] = *reinterpret_cast<const uint4*>(bp + 8);
    }
    __syncthreads();
#pragma unroll
    for (int j = 0; j < 4; ++j)
      *reinterpret_cast<uint4*>(&As[ar * LDA + ako + j * 8]) = av[j];
#pragma unroll
    for (int p = 0; p < BP; ++p) {
      *reinterpret_cast<uint4*>(&Bs[(p * 64 + br0) * LDA + bo])     = bv[p * 2];
      *reinterpret_cast<uint4*>(&Bs[(p * 64 + br0) * LDA + bo + 8]) = bv[p * 2 + 1];
    }
    __syncthreads();

#pragma unroll
    for (int kk = 0; kk < 64; kk += 32) {
      s16x8 af[2];
#pragma unroll
      for (int rf = 0; rf < 2; ++rf)
        af[rf] = *reinterpret_cast<const s16x8*>(&As[(wv * 32 + rf * 16 + lr) * LDA + kk + lg * 8]);
#pragma unroll
      for (int f = 0; f < BN / 16; ++f) {
        s16x8 bf = *reinterpret_cast<const s16x8*>(&Bs[(f * 16 + lr) * LDA + kk + lg * 8]);
        acc[0][f] = __builtin_amdgcn_mfma_f32_16x16x32_bf16(af[0], bf, acc[0][f], 0, 0, 0);
        acc[1][f] = __builtin_amdgcn_mfma_f32_16x16x32_bf16(af[1], bf, acc[1][f], 0, 0, 0);
      }
    }
  }

  float bcv[BN / 16], bdv[BN / 16];
#pragma unroll
  for (int f = 0; f < BN / 16; ++f) {
    int col = f * 16 + lr;
    bcv[f] = bc ? bc[col] : 0.f;
    bdv[f] = bd ? bd[col] : 0.f;
  }

#pragma unroll
  for (int rf = 0; rf < 2; ++rf)
#pragma unroll
    for (int rr = 0; rr < 4; ++rr) {
      int grow = bm0 + wv * 32 + rf * 16 + lg * 4 + rr;
      if (grow >= M) continue;
      float dgr = degf[grow];
#pragma unroll
      for (int f = 0; f < BN / 16; ++f) {
        int col = f * 16 + lr;
        float v = acc[rf][f][rr] + bcv[f] + dgr * bdv[f];
        if (col < SPLIT) {
          if (outb0) outb0[(size_t)grow * SPLIT + col] = f2b(v);
          if (outf0) outf0[(size_t)grow * SPLIT + col] = v;
        } else {
          outb1[(size_t)grow * (BN - SPLIT) + (col - SPLIT)] = f2b(v);
        }
      }
    }
}

// ---------------- sorted-batch pooling (f32, width 128) ----------------
__global__ void k_pool(const float* __restrict__ src, const int* __restrict__ batch,
                       float* __restrict__ dst, int n) {
  int c = threadIdx.x;
  int n0 = blockIdx.x * 128;
  if (n0 >= n) return;
  int n1 = n0 + 128; if (n1 > n) n1 = n;
  float acc = 0.f;
  int cur = batch[n0];
  for (int i = n0; i < n1; ++i) {
    int bi = batch[i];
    if (bi != cur) { atomicAdd(&dst[cur * 128 + c], acc); acc = 0.f; cur = bi; }
    acc += src[(size_t)i * 128 + c];
  }
  atomicAdd(&dst[cur * 128 + c], acc);
}

// ---------------- sorted-batch pooling (bf16 in, width 64) ----------------
__global__ void k_pool64(const u16* __restrict__ src, const int* __restrict__ batch,
                         float* __restrict__ dst, int n) {
  int c = threadIdx.x;
  int n0 = blockIdx.x * 128;
  if (n0 >= n) return;
  int n1 = n0 + 128; if (n1 > n) n1 = n;
  float acc = 0.f;
  int cur = batch[n0];
  for (int i = n0; i < n1; ++i) {
    int bi = batch[i];
    if (bi != cur) { atomicAdd(&dst[cur * 64 + c], acc); acc = 0.f; cur = bi; }
    acc += b2f(src[(size_t)i * 64 + c]);
  }
  atomicAdd(&dst[cur * 64 + c], acc);
}

// ---------------- sorted-batch pooling (f32 scalar) ----------------
__global__ void k_pool1(const float* __restrict__ src, const int* __restrict__ batch,
                        float* __restrict__ dst, int n) {
  if (threadIdx.x != 0) return;
  int n0 = blockIdx.x * 128;
  if (n0 >= n) return;
  int n1 = n0 + 128; if (n1 > n) n1 = n;
  float acc = 0.f;
  int cur = batch[n0];
  for (int i = n0; i < n1; ++i) {
    int bi = batch[i];
    if (bi != cur) { atomicAdd(&dst[cur], acc); acc = 0.f; cur = bi; }
    acc += src[i];
  }
  atomicAdd(&dst[cur], acc);
}

// ---------------- head: msg_pool + global MLP + final MLP, one block per graph ----------------
__global__ void k_head(const float* __restrict__ npool, const float* __restrict__ PadjX,
                       const float* __restrict__ PaggE, const float* __restrict__ pdeg,
                       const float* __restrict__ G1a, const float* __restrict__ G1b,
                       const float* __restrict__ e1,
                       const float* __restrict__ g2W0, const float* __restrict__ g2b0,
                       const float* __restrict__ g2W1, const float* __restrict__ g2b1,
                       const float* __restrict__ fW0, const float* __restrict__ fb0,
                       const float* __restrict__ fW1, const float* __restrict__ fb1,
                       float* __restrict__ out) {
  __shared__ float r0[256], r1[128], r2[128], r3[256], red[256];
  int b = blockIdx.x, t = threadIdx.x;
  if (t < 128) {
    float a = pdeg[b] * e1[t];
    for (int k = 0; k < 128; ++k) a = fmaf(PadjX[(size_t)b * 128 + k], G1a[(size_t)k * 128 + t], a);
    for (int k = 0; k < 64;  ++k) a = fmaf(PaggE[(size_t)b * 64 + k],  G1b[(size_t)k * 128 + t], a);
    r0[128 + t] = a;
    r0[t] = npool[(size_t)b * 128 + t];
  }
  __syncthreads();
  if (t < 128) {
    float a = g2b0[t];
    for (int k = 0; k < 256; ++k) a = fmaf(r0[k], g2W0[(size_t)k * 128 + t], a);
    r1[t] = a;
  }
  __syncthreads();
  if (t < 128) {
    float a = g2b1[t];
    for (int k = 0; k < 128; ++k) a = fmaf(r1[k], g2W1[(size_t)k * 128 + t], a);
    r2[t] = a;
  }
  __syncthreads();
  {
    float a = fb0[t];
    for (int k = 0; k < 128; ++k) a = fmaf(r2[k], fW0[(size_t)k * 256 + t], a);
    r3[t] = a;
  }
  __syncthreads();
  red[t] = r3[t] * fW1[t];
  __syncthreads();
  for (int s = 128; s > 0; s >>= 1) {
    if (t < s) red[t] += red[t + s];
    __syncthreads();
  }
  if (t == 0) out[b] = red[0] + fb1[0];
}

extern "C" void kernel_launch(void* const* d_in, const int* in_sizes, int n_in,
                              void* d_out, int out_size, void* d_ws, size_t ws_size,
                              hipStream_t stream) {
  const float* x     = (const float*)d_in[0];
  const int*   eidx  = (const int*)d_in[1];
  const float* eattr = (const float*)d_in[2];
  const int*   batch = (const int*)d_in[3];
  const float* eW0 = (const float*)d_in[4];  const float* eb0 = (const float*)d_in[5];
  const float* eW1 = (const float*)d_in[6];  const float* eb1 = (const float*)d_in[7];
  const float* n1W0 = (const float*)d_in[8]; const float* n1b0 = (const float*)d_in[9];
  const float* n1W1 = (const float*)d_in[10];const float* n1b1 = (const float*)d_in[11];
  const float* n2W0 = (const float*)d_in[12];const float* n2b0 = (const float*)d_in[13];
  const float* n2W1 = (const float*)d_in[14];const float* n2b1 = (const float*)d_in[15];
  const float* g1W0 = (const float*)d_in[16];const float* g1b0 = (const float*)d_in[17];
  const float* g1W1 = (const float*)d_in[18];const float* g1b1 = (const float*)d_in[19];
  const float* g2W0 = (const float*)d_in[20];const float* g2b0 = (const float*)d_in[21];
  const float* g2W1 = (const float*)d_in[22];const float* g2b1 = (const float*)d_in[23];
  const float* fW0 = (const float*)d_in[24]; const float* fb0 = (const float*)d_in[25];
  const float* fW1 = (const float*)d_in[26]; const float* fb1 = (const float*)d_in[27];

  const int* rowv = eidx;
  const int* colv = eidx + N_EDGES;

  char* ws = (char*)d_ws;
  size_t off = 0;
  auto alloc = [&](size_t bytes) -> void* {
    void* p = ws + off; off = (off + bytes + 255) & ~(size_t)255; return p;
  };
  u16*   x_b    = (u16*)alloc((size_t)N_NODES * 128 * 2);
  float* x_f    = (float*)alloc((size_t)N_NODES * 128 * 4);
  u16*   adjX_b = (u16*)alloc((size_t)N_NODES * 128 * 2);
  u16*   aggE_b = (u16*)alloc((size_t)N_NODES * 64 * 2);
  float* degf   = (float*)alloc((size_t)N_NODES * 4);
  int*   rowptr = (int*)alloc((size_t)(N_NODES + 1) * 4);
  int*   crow   = (int*)alloc((size_t)N_EDGES * 4);
  int*   ceid   = (int*)alloc((size_t)N_EDGES * 4);
  // ---- zeroed region (single memset) ----
  char*  zstart = ws + off;
  int*   cursor = (int*)alloc((size_t)N_NODES * 4);
  float* cnt    = (float*)alloc((size_t)N_NODES * 64 * 4);
  float* npool  = (float*)alloc((size_t)NB * 128 * 4);
  float* PadjX  = (float*)alloc((size_t)NB * 128 * 4);
  float* PaggE  = (float*)alloc((size_t)NB * 64 * 4);
  float* pdeg   = (float*)alloc((size_t)NB * 4);
  size_t zbytes = (size_t)((ws + off) - zstart);
  // ---- f32 weight-composition scratch ----
  float* N1a   = (float*)alloc(128 * 128 * 4);
  float* N1b   = (float*)alloc(64 * 128 * 4);
  float* N2a   = (float*)alloc(128 * 128 * 4);
  float* N2b   = (float*)alloc(128 * 128 * 4);
  float* A1    = (float*)alloc(128 * 64 * 4);
  float* B1    = (float*)alloc(128 * 64 * 4);
  float* C1    = (float*)alloc(64 * 64 * 4);
  float* G1a   = (float*)alloc(128 * 128 * 4);
  float* G1b   = (float*)alloc(64 * 128 * 4);
  float* T1    = (float*)alloc(64 * 128 * 4);
  float* U1    = (float*)alloc(128 * 128 * 4);
  float* WadjX = (float*)alloc(128 * 128 * 4);
  float* WaggE = (float*)alloc(64 * 128 * 4);
  float* Wdegx = (float*)alloc(128 * 128 * 4);
  float* c0    = (float*)alloc(64 * 4);
  float* d1    = (float*)alloc(128 * 4);
  float* d2    = (float*)alloc(128 * 4);
  float* tmpv  = (float*)alloc(128 * 4);
  float* ddeg  = (float*)alloc(128 * 4);
  float* e1    = (float*)alloc(128 * 4);
  float* bc    = (float*)alloc(192 * 4);
  float* bd    = (float*)alloc(192 * 4);
  u16*   BigWt = (u16*)alloc((size_t)192 * 448 * 2);
  (void)ws_size; (void)in_sizes; (void)n_in; (void)out_size;

  // ---- one memset for everything needing zeros ----
  hipMemsetAsync(zstart, 0, zbytes, stream);

  // x -> bf16
  k_f2b<<<(N_NODES * 128 + 255) / 256, 256, 0, stream>>>(x, x_b, N_NODES * 128);

  // ---- weight composition, level-batched ----
  {
    MMBatch L1{};
    L1.op[0]  = {n1W0, n1W1, nullptr, N1a, 128, 0,   128, 128, 128, 128};
    L1.op[1]  = {n1W0, n1W1, nullptr, N1b, 128, 128, 128, 128, 128, 64};
    L1.op[2]  = {n2W0, n2W1, nullptr, N2a, 128, 0,   128, 128, 128, 128};
    L1.op[3]  = {n2W0, n2W1, nullptr, N2b, 128, 128, 128, 128, 128, 128};
    L1.op[4]  = {eW0,  eW1,  nullptr, A1,  128, 0,   64,  128, 64,  128};
    L1.op[5]  = {eW0,  eW1,  nullptr, B1,  128, 128, 64,  128, 64,  128};
    L1.op[6]  = {eW0,  eW1,  nullptr, C1,  128, 256, 64,  128, 64,  64};
    L1.op[7]  = {g1W0, g1W1, nullptr, G1a, 128, 0,   128, 128, 128, 128};
    L1.op[8]  = {g1W0, g1W1, nullptr, G1b, 128, 128, 128, 128, 128, 64};
    L1.op[9]  = {eb0,  eW1,  eb1,     c0,  128, 0,   64,  128, 64,  1};
    L1.op[10] = {n1b0, n1W1, n1b1,    d1,  128, 0,   128, 128, 128, 1};
    L1.op[11] = {n2b0, n2W1, n2b1,    d2,  128, 0,   128, 128, 128, 1};
    L1.op[12] = {g1b0, g1W1, g1b1,    e1,  128, 0,   128, 128, 128, 1};
    k_mmb<<<dim3(128, 13), 128, 0, stream>>>(L1);

    MMBatch L2{};
    L2.op[0] = {N1b, N2b, nullptr, T1, 128, 0, 128, 128, 128, 64};
    L2.op[1] = {N1a, N2b, nullptr, U1, 128, 0, 128, 128, 128, 128};
    for (int j = 2; j < 13; ++j) L2.op[j] = {nullptr, nullptr, nullptr, nullptr, 0, 0, 0, 0, 0, 0};
    k_mmb<<<dim3(128, 2), 128, 0, stream>>>(L2);

    MMBatch L3{};
    L3.op[0] = {A1, T1, U1,      WadjX, 64,  0, 128, 64,  128, 128};
    L3.op[1] = {C1, T1, nullptr, WaggE, 64,  0, 128, 64,  128, 64};
    L3.op[2] = {B1, T1, nullptr, Wdegx, 64,  0, 128, 64,  128, 128};
    L3.op[3] = {c0, T1, nullptr, tmpv,  64,  0, 128, 64,  128, 1};
    for (int j = 4; j < 13; ++j) L3.op[j] = {nullptr, nullptr, nullptr, nullptr, 0, 0, 0, 0, 0, 0};
    k_mmb<<<dim3(128, 4), 128, 0, stream>>>(L3);

    k_mm<<<1, 128, 0, stream>>>(d1, 128, 0, N2b, 128, tmpv, ddeg, 128, 128);
  }
  k_pack_iter<<<(192 * 448 + 255) / 256, 256, 0, stream>>>(N2a, WadjX, A1, WaggE, C1, Wdegx, B1, BigWt);
  k_packbias<<<1, 192, 0, stream>>>(d2, ddeg, c0, bc, bd);

  // ---- CSR over col + cnt matrix ----
  k_hist<<<(N_EDGES + 255) / 256, 256, 0, stream>>>(colv, cursor);
  k_scan<<<1, 1024, 0, stream>>>(cursor, rowptr, cursor, degf, N_NODES);
  k_fill<<<(N_EDGES + 255) / 256, 256, 0, stream>>>(rowv, colv, cursor, crow, ceid);
  k_cnt<<<(N_EDGES + 255) / 256, 256, 0, stream>>>(rowv, colv, batch, cnt);

  const int GN = (N_NODES + 127) / 128;    // 391

  Chunks chIter;
  chIter.src[0] = x_b;    chIter.width[0] = 128; chIter.koff[0] = 0;  chIter.scl[0] = 0;
  chIter.src[1] = x_b;    chIter.width[1] = 128; chIter.koff[1] = 64; chIter.scl[1] = 0;
  chIter.src[2] = adjX_b; chIter.width[2] = 128; chIter.koff[2] = 0;  chIter.scl[2] = 0;
  chIter.src[3] = adjX_b; chIter.width[3] = 128; chIter.koff[3] = 64; chIter.scl[3] = 0;
  chIter.src[4] = aggE_b; chIter.width[4] = 64;  chIter.koff[4] = 0;  chIter.scl[4] = 0;
  chIter.src[5] = x_b;    chIter.width[5] = 128; chIter.koff[5] = 0;  chIter.scl[5] = 1;
  chIter.src[6] = x_b;    chIter.width[6] = 128; chIter.koff[6] = 64; chIter.scl[6] = 1;

  // ---- iteration 1 ----
  k_agg<true><<<2048, 256, 0, stream>>>(x_b, eattr, rowptr, crow, ceid, adjX_b, aggE_b);
  gemm_fused<192, 7><<<GN, 256, 0, stream>>>(BigWt, 448, bc, bd, degf, chIter, N_NODES, 128,
                                             x_b, nullptr, aggE_b);
  // ---- iteration 2 ----
  k_agg<false><<<2048, 256, 0, stream>>>(x_b, nullptr, rowptr, crow, ceid, adjX_b, nullptr);
  gemm_fused<192, 7><<<GN, 256, 0, stream>>>(BigWt, 448, bc, bd, degf, chIter, N_NODES, 128,
                                             x_b, x_f, aggE_b);

  // ---- pooled GlobalModel path (no per-node gagg) ----
  k_cntgemm<<<128, 256, 0, stream>>>(cnt, x_b, PadjX);
  k_pool<<<GN, 128, 0, stream>>>(x_f, batch, npool, N_NODES);
  k_pool64<<<GN, 64, 0, stream>>>(aggE_b, batch, PaggE, N_NODES);
  k_pool1<<<GN, 64, 0, stream>>>(degf, batch, pdeg, N_NODES);

  // ---- head: msg_pool + global MLP + final MLP ----
  k_head<<<NB, 256, 0, stream>>>(npool, PadjX, PaggE, pdeg, G1a, G1b, e1,
                                 g2W0, g2b0, g2W1, g2b1, fW0, fb0, fW1, fb1,
                                 (float*)d_out);
}

// Round 7
// 682.412 us; speedup vs baseline: 2.9035x; 1.1364x over previous
//
#include <hip/hip_runtime.h>
#include <hip/hip_bf16.h>

#define N_NODES 50000
#define N_EDGES 400000
#define NB 64

typedef unsigned short u16;
typedef unsigned int u32;
typedef __attribute__((ext_vector_type(8))) short s16x8;
typedef __attribute__((ext_vector_type(4))) float f32x4;

__device__ __forceinline__ u16 f2b(float f) {
  __hip_bfloat16 h = __float2bfloat16(f);
  return *reinterpret_cast<const u16*>(&h);
}
__device__ __forceinline__ float b2f(u16 u) {
  u32 v = ((u32)u) << 16;
  return *reinterpret_cast<const float*>(&v);
}

// ---------------- elementwise f32 -> bf16 ----------------
__global__ void k_f2b(const float* __restrict__ in, u16* __restrict__ out, int n) {
  int i = blockIdx.x * 256 + threadIdx.x;
  if (i < n) out[i] = f2b(in[i]);
}

// ---------------- batched small f32 matmuls ----------------
struct MMOp { const float* A; const float* B; const float* add; float* C;
              int lda, r0, ldb, K2, N, rows; };
struct MMBatch { MMOp op[13]; };

__global__ void k_mmb(MMBatch mb) {
  MMOp o = mb.op[blockIdx.y];
  int i = blockIdx.x;
  int n = threadIdx.x;
  if (i >= o.rows || n >= o.N) return;
  float acc = o.add ? o.add[(size_t)i * o.N + n] : 0.f;
  for (int k = 0; k < o.K2; ++k)
    acc = fmaf(o.A[(size_t)(o.r0 + i) * o.lda + k], o.B[(size_t)k * o.ldb + n], acc);
  o.C[(size_t)i * o.N + n] = acc;
}

__global__ void k_mm(const float* __restrict__ A, int lda, int r0,
                     const float* __restrict__ B, int ldb,
                     const float* __restrict__ add, float* __restrict__ C,
                     int K2, int N) {
  int i = blockIdx.x, n = threadIdx.x;
  if (n >= N) return;
  float acc = add ? add[(size_t)i * N + n] : 0.f;
  for (int k = 0; k < K2; ++k)
    acc = fmaf(A[(size_t)(r0 + i) * lda + k], B[(size_t)k * ldb + n], acc);
  C[(size_t)i * N + n] = acc;
}

// ---------------- pack composed weights (bf16, N-major rows of K) ----------------
__global__ void k_pack_iter(const float* __restrict__ N2a, const float* __restrict__ WadjX,
                            const float* __restrict__ A1, const float* __restrict__ WaggE,
                            const float* __restrict__ C1, const float* __restrict__ Wdegx,
                            const float* __restrict__ B1, u16* __restrict__ Wt) {
  int i = blockIdx.x * 256 + threadIdx.x;
  if (i >= 192 * 448) return;
  int n = i / 448, k = i % 448;
  float v;
  if (k < 128)      v = (n < 128) ? N2a[(size_t)k * 128 + n] : 0.f;
  else if (k < 256) { int kk = k - 128; v = (n < 128) ? WadjX[(size_t)kk * 128 + n] : A1[(size_t)kk * 64 + (n - 128)]; }
  else if (k < 320) { int kk = k - 256; v = (n < 128) ? WaggE[(size_t)kk * 128 + n] : C1[(size_t)kk * 64 + (n - 128)]; }
  else              { int kk = k - 320; v = (n < 128) ? Wdegx[(size_t)kk * 128 + n] : B1[(size_t)kk * 64 + (n - 128)]; }
  Wt[(size_t)n * 448 + k] = f2b(v);
}

__global__ void k_packbias(const float* __restrict__ d2, const float* __restrict__ ddeg,
                           const float* __restrict__ c0, float* __restrict__ bc,
                           float* __restrict__ bd) {
  int t = threadIdx.x;
  if (t >= 192) return;
  bc[t] = (t < 128) ? d2[t] : 0.f;
  bd[t] = (t < 128) ? ddeg[t] : c0[t - 128];
}

// ---------------- CSR build over col ----------------
__global__ void k_hist(const int* __restrict__ colv, int* __restrict__ deg) {
  int i = blockIdx.x * 256 + threadIdx.x;
  if (i < N_EDGES) atomicAdd(&deg[colv[i]], 1);
}

// deg aliases cursor: read deg[i] then write cursor[i] (same thread, in order)
__global__ void k_scan(const int* __restrict__ deg, int* __restrict__ rowptr,
                       int* __restrict__ cursor, float* __restrict__ degf, int n) {
  __shared__ int part[1024];
  int t = threadIdx.x;
  int chunk = (n + 1023) / 1024;
  int lo = t * chunk, hi = lo + chunk; if (hi > n) hi = n;
  if (lo > n) lo = n;
  int s = 0;
  for (int i = lo; i < hi; ++i) s += deg[i];
  part[t] = s;
  __syncthreads();
  for (int d = 1; d < 1024; d <<= 1) {
    int v = (t >= d) ? part[t - d] : 0;
    __syncthreads();
    part[t] += v;
    __syncthreads();
  }
  int base = (t == 0) ? 0 : part[t - 1];
  for (int i = lo; i < hi; ++i) {
    int d = deg[i];
    rowptr[i] = base;
    cursor[i] = base;
    degf[i] = (float)d;
    base += d;
  }
  if (t == 1023) rowptr[n] = part[1023];
}

__global__ void k_fill(const int* __restrict__ rowv, const int* __restrict__ colv,
                       int* __restrict__ cursor, int* __restrict__ crow, int* __restrict__ ceid) {
  int i = blockIdx.x * 256 + threadIdx.x;
  if (i >= N_EDGES) return;
  int pos = atomicAdd(&cursor[colv[i]], 1);
  crow[pos] = rowv[i];
  ceid[pos] = i;
}

// ---------------- cnt[v][b] = #edges with row=v, batch[col]=b ----------------
__global__ void k_cnt(const int* __restrict__ rowv, const int* __restrict__ colv,
                      const int* __restrict__ batch, float* __restrict__ cnt) {
  int e = blockIdx.x * 256 + threadIdx.x;
  if (e >= N_EDGES) return;
  atomicAdd(&cnt[(size_t)rowv[e] * 64 + batch[colv[e]]], 1.0f);
}

// ---------------- Ppart[blk][b*128+c] = sum_{v in span} cnt[v][b] * x2[v][c] ----------------
#define CGB 512
__global__ __launch_bounds__(256)
void k_cntgemm(const float* __restrict__ cnt, const u16* __restrict__ xb,
               float* __restrict__ Ppart) {
  __shared__ float cs[8][64];
  int t = threadIdx.x, c = t & 127, half = t >> 7;
  float acc[32];
#pragma unroll
  for (int q = 0; q < 32; ++q) acc[q] = 0.f;
  int span = (N_NODES + CGB - 1) / CGB;
  int v0 = blockIdx.x * span;
  int v1 = v0 + span; if (v1 > N_NODES) v1 = N_NODES;
  for (int vt = v0; vt < v1; vt += 8) {
    int nv = v1 - vt; if (nv > 8) nv = 8;
    for (int idx = t; idx < nv * 64; idx += 256)
      cs[idx >> 6][idx & 63] = cnt[(size_t)(vt + (idx >> 6)) * 64 + (idx & 63)];
    __syncthreads();
    for (int j = 0; j < nv; ++j) {
      float xv = b2f(xb[(size_t)(vt + j) * 128 + c]);
#pragma unroll
      for (int q = 0; q < 32; ++q) acc[q] = fmaf(cs[j][half * 32 + q], xv, acc[q]);
    }
    __syncthreads();
  }
#pragma unroll
  for (int q = 0; q < 32; ++q)
    Ppart[(size_t)blockIdx.x * 8192 + (size_t)(half * 32 + q) * 128 + c] = acc[q];
}

// ---------------- reduce partials: P[i] = sum_blk Ppart[blk][i] ----------------
__global__ void k_pred(const float* __restrict__ Ppart, float* __restrict__ P) {
  int i = blockIdx.x * 256 + threadIdx.x;   // 8192 threads
  float s = 0.f;
  for (int k = 0; k < CGB; ++k) s += Ppart[(size_t)k * 8192 + i];
  P[i] = s;
}

// ---------------- CSR gather segment-sums (4-way unrolled) ----------------
template<bool DOE>
__global__ void k_agg(const u16* __restrict__ xb, const float* __restrict__ eaf,
                      const int* __restrict__ rowptr, const int* __restrict__ crow,
                      const int* __restrict__ ceid,
                      u16* __restrict__ outX, u16* __restrict__ outE) {
  int wpb = blockDim.x >> 6;
  int w = blockIdx.x * wpb + (threadIdx.x >> 6);
  int l = threadIdx.x & 63;
  int nw = gridDim.x * wpb;
  for (int v = w; v < N_NODES; v += nw) {
    int s = rowptr[v], e1 = rowptr[v + 1];
    float ax0 = 0.f, ax1 = 0.f, ae = 0.f;
    int i = s;
    for (; i + 3 < e1; i += 4) {
      int r0 = crow[i], r1 = crow[i + 1], r2 = crow[i + 2], r3 = crow[i + 3];
      u32 a0 = *reinterpret_cast<const u32*>(&xb[(size_t)r0 * 128 + l * 2]);
      u32 a1 = *reinterpret_cast<const u32*>(&xb[(size_t)r1 * 128 + l * 2]);
      u32 a2 = *reinterpret_cast<const u32*>(&xb[(size_t)r2 * 128 + l * 2]);
      u32 a3 = *reinterpret_cast<const u32*>(&xb[(size_t)r3 * 128 + l * 2]);
      float e0, ev1, ev2, ev3;
      if (DOE) {
        int q0 = ceid[i], q1 = ceid[i + 1], q2 = ceid[i + 2], q3 = ceid[i + 3];
        e0  = eaf[(size_t)q0 * 64 + l];
        ev1 = eaf[(size_t)q1 * 64 + l];
        ev2 = eaf[(size_t)q2 * 64 + l];
        ev3 = eaf[(size_t)q3 * 64 + l];
      }
      ax0 += b2f((u16)(a0 & 0xffff)) + b2f((u16)(a1 & 0xffff))
           + b2f((u16)(a2 & 0xffff)) + b2f((u16)(a3 & 0xffff));
      ax1 += b2f((u16)(a0 >> 16)) + b2f((u16)(a1 >> 16))
           + b2f((u16)(a2 >> 16)) + b2f((u16)(a3 >> 16));
      if (DOE) ae += e0 + ev1 + ev2 + ev3;
    }
    for (; i < e1; ++i) {
      u32 a = *reinterpret_cast<const u32*>(&xb[(size_t)crow[i] * 128 + l * 2]);
      ax0 += b2f((u16)(a & 0xffff));
      ax1 += b2f((u16)(a >> 16));
      if (DOE) ae += eaf[(size_t)ceid[i] * 64 + l];
    }
    u32 pk = ((u32)f2b(ax1) << 16) | (u32)f2b(ax0);
    *reinterpret_cast<u32*>(&outX[(size_t)v * 128 + l * 2]) = pk;
    if (DOE) outE[(size_t)v * 64 + l] = f2b(ae);
  }
}

// ---------------- fused node GEMM over concatenated K-chunks of 64 ----------------
struct Chunks { const u16* src[7]; int width[7]; int koff[7]; int scl[7]; };

template<int BM, int BN, int NCH>
__global__ __launch_bounds__(256)
void gemm_fused(const u16* __restrict__ Wt, int KTOT,
                const float* __restrict__ bc, const float* __restrict__ bd,
                const float* __restrict__ degf, Chunks ch, int M, int SPLIT,
                u16* __restrict__ outb0, u16* __restrict__ outb1)
{
  constexpr int LDA = 72;
  constexpr int BP = BN / 64;          // B-staging passes
  constexpr int RF = BM / 64;          // A row-fragments per wave
  constexpr int AE = BM / 4;           // A elems staged per thread
  constexpr int AV = AE / 8;           // uint4s per thread
  __shared__ u16 As[BM * LDA];
  __shared__ u16 Bs[BN * LDA];

  const int t = threadIdx.x;
  const int wv = t >> 6, lane = t & 63, lr = lane & 15, lg = lane >> 4;
  const int bm0 = blockIdx.x * BM;
  const int wb = wv * (BM / 4);        // wave's row base

  f32x4 acc[RF][BN / 16];
#pragma unroll
  for (int a = 0; a < RF; ++a)
#pragma unroll
    for (int b = 0; b < BN / 16; ++b) acc[a][b] = (f32x4){0.f, 0.f, 0.f, 0.f};

  const int ar = t & (BM - 1);
  const int ako = (t / BM) * AE;
  int agrow = bm0 + ar;
  if (agrow >= M) agrow = M - 1;
  const float dg_a = degf[agrow];

  const int br0 = t >> 2;
  const int bo  = (t & 3) * 16;

#pragma unroll
  for (int c = 0; c < NCH; ++c) {
    const u16* ap = ch.src[c] + (size_t)agrow * ch.width[c] + ch.koff[c] + ako;
    uint4 av[AV];
#pragma unroll
    for (int j = 0; j < AV; ++j) av[j] = *reinterpret_cast<const uint4*>(ap + j * 8);
    if (ch.scl[c]) {
#pragma unroll
      for (int j = 0; j < AV; ++j) {
        u32* p = reinterpret_cast<u32*>(&av[j]);
#pragma unroll
        for (int q = 0; q < 4; ++q) {
          u32 w = p[q];
          float lo = b2f((u16)(w & 0xffff)) * dg_a;
          float hi = b2f((u16)(w >> 16)) * dg_a;
          p[q] = ((u32)f2b(hi) << 16) | (u32)f2b(lo);
        }
      }
    }
    uint4 bv[BP * 2];
#pragma unroll
    for (int p = 0; p < BP; ++p) {
      const u16* bp = Wt + (size_t)(p * 64 + br0) * KTOT + c * 64 + bo;
      bv[p * 2]     = *reinterpret_cast<const uint4*>(bp);
      bv[p * 2 + 1] = *reinterpret_cast<const uint4*>(bp + 8);
    }
    __syncthreads();
#pragma unroll
    for (int j = 0; j < AV; ++j)
      *reinterpret_cast<uint4*>(&As[ar * LDA + ako + j * 8]) = av[j];
#pragma unroll
    for (int p = 0; p < BP; ++p) {
      *reinterpret_cast<uint4*>(&Bs[(p * 64 + br0) * LDA + bo])     = bv[p * 2];
      *reinterpret_cast<uint4*>(&Bs[(p * 64 + br0) * LDA + bo + 8]) = bv[p * 2 + 1];
    }
    __syncthreads();

#pragma unroll
    for (int kk = 0; kk < 64; kk += 32) {
      s16x8 af[RF];
#pragma unroll
      for (int rf = 0; rf < RF; ++rf)
        af[rf] = *reinterpret_cast<const s16x8*>(&As[(wb + rf * 16 + lr) * LDA + kk + lg * 8]);
#pragma unroll
      for (int f = 0; f < BN / 16; ++f) {
        s16x8 bf = *reinterpret_cast<const s16x8*>(&Bs[(f * 16 + lr) * LDA + kk + lg * 8]);
#pragma unroll
        for (int rf = 0; rf < RF; ++rf)
          acc[rf][f] = __builtin_amdgcn_mfma_f32_16x16x32_bf16(af[rf], bf, acc[rf][f], 0, 0, 0);
      }
    }
  }

  float bcv[BN / 16], bdv[BN / 16];
#pragma unroll
  for (int f = 0; f < BN / 16; ++f) {
    int col = f * 16 + lr;
    bcv[f] = bc ? bc[col] : 0.f;
    bdv[f] = bd ? bd[col] : 0.f;
  }

#pragma unroll
  for (int rf = 0; rf < RF; ++rf)
#pragma unroll
    for (int rr = 0; rr < 4; ++rr) {
      int grow = bm0 + wb + rf * 16 + lg * 4 + rr;
      if (grow >= M) continue;
      float dgr = degf[grow];
#pragma unroll
      for (int f = 0; f < BN / 16; ++f) {
        int col = f * 16 + lr;
        float v = acc[rf][f][rr] + bcv[f] + dgr * bdv[f];
        if (col < SPLIT) {
          outb0[(size_t)grow * SPLIT + col] = f2b(v);
        } else {
          outb1[(size_t)grow * (BN - SPLIT) + (col - SPLIT)] = f2b(v);
        }
      }
    }
}

// ---------------- sorted-batch pooling (bf16 in, width 128) ----------------
__global__ void k_pool128b(const u16* __restrict__ src, const int* __restrict__ batch,
                           float* __restrict__ dst, int n) {
  int c = threadIdx.x;
  int n0 = blockIdx.x * 128;
  if (n0 >= n) return;
  int n1 = n0 + 128; if (n1 > n) n1 = n;
  float acc = 0.f;
  int cur = batch[n0];
  for (int i = n0; i < n1; ++i) {
    int bi = batch[i];
    if (bi != cur) { atomicAdd(&dst[cur * 128 + c], acc); acc = 0.f; cur = bi; }
    acc += b2f(src[(size_t)i * 128 + c]);
  }
  atomicAdd(&dst[cur * 128 + c], acc);
}

// ---------------- sorted-batch pooling (bf16 in, width 64) ----------------
__global__ void k_pool64(const u16* __restrict__ src, const int* __restrict__ batch,
                         float* __restrict__ dst, int n) {
  int c = threadIdx.x;
  int n0 = blockIdx.x * 128;
  if (n0 >= n) return;
  int n1 = n0 + 128; if (n1 > n) n1 = n;
  float acc = 0.f;
  int cur = batch[n0];
  for (int i = n0; i < n1; ++i) {
    int bi = batch[i];
    if (bi != cur) { atomicAdd(&dst[cur * 64 + c], acc); acc = 0.f; cur = bi; }
    acc += b2f(src[(size_t)i * 64 + c]);
  }
  atomicAdd(&dst[cur * 64 + c], acc);
}

// ---------------- sorted-batch pooling (f32 scalar) ----------------
__global__ void k_pool1(const float* __restrict__ src, const int* __restrict__ batch,
                        float* __restrict__ dst, int n) {
  if (threadIdx.x != 0) return;
  int n0 = blockIdx.x * 128;
  if (n0 >= n) return;
  int n1 = n0 + 128; if (n1 > n) n1 = n;
  float acc = 0.f;
  int cur = batch[n0];
  for (int i = n0; i < n1; ++i) {
    int bi = batch[i];
    if (bi != cur) { atomicAdd(&dst[cur], acc); acc = 0.f; cur = bi; }
    acc += src[i];
  }
  atomicAdd(&dst[cur], acc);
}

// ---------------- head: msg_pool + global MLP + final MLP, one block per graph ----------------
__global__ void k_head(const float* __restrict__ npool, const float* __restrict__ PadjX,
                       const float* __restrict__ PaggE, const float* __restrict__ pdeg,
                       const float* __restrict__ G1a, const float* __restrict__ G1b,
                       const float* __restrict__ e1,
                       const float* __restrict__ g2W0, const float* __restrict__ g2b0,
                       const float* __restrict__ g2W1, const float* __restrict__ g2b1,
                       const float* __restrict__ fW0, const float* __restrict__ fb0,
                       const float* __restrict__ fW1, const float* __restrict__ fb1,
                       float* __restrict__ out) {
  __shared__ float r0[256], r1[128], r2[128], r3[256], red[256];
  int b = blockIdx.x, t = threadIdx.x;
  if (t < 128) {
    float a = pdeg[b] * e1[t];
    for (int k = 0; k < 128; ++k) a = fmaf(PadjX[(size_t)b * 128 + k], G1a[(size_t)k * 128 + t], a);
    for (int k = 0; k < 64;  ++k) a = fmaf(PaggE[(size_t)b * 64 + k],  G1b[(size_t)k * 128 + t], a);
    r0[128 + t] = a;
    r0[t] = npool[(size_t)b * 128 + t];
  }
  __syncthreads();
  if (t < 128) {
    float a = g2b0[t];
    for (int k = 0; k < 256; ++k) a = fmaf(r0[k], g2W0[(size_t)k * 128 + t], a);
    r1[t] = a;
  }
  __syncthreads();
  if (t < 128) {
    float a = g2b1[t];
    for (int k = 0; k < 128; ++k) a = fmaf(r1[k], g2W1[(size_t)k * 128 + t], a);
    r2[t] = a;
  }
  __syncthreads();
  {
    float a = fb0[t];
    for (int k = 0; k < 128; ++k) a = fmaf(r2[k], fW0[(size_t)k * 256 + t], a);
    r3[t] = a;
  }
  __syncthreads();
  red[t] = r3[t] * fW1[t];
  __syncthreads();
  for (int s = 128; s > 0; s >>= 1) {
    if (t < s) red[t] += red[t + s];
    __syncthreads();
  }
  if (t == 0) out[b] = red[0] + fb1[0];
}

extern "C" void kernel_launch(void* const* d_in, const int* in_sizes, int n_in,
                              void* d_out, int out_size, void* d_ws, size_t ws_size,
                              hipStream_t stream) {
  const float* x     = (const float*)d_in[0];
  const int*   eidx  = (const int*)d_in[1];
  const float* eattr = (const float*)d_in[2];
  const int*   batch = (const int*)d_in[3];
  const float* eW0 = (const float*)d_in[4];  const float* eb0 = (const float*)d_in[5];
  const float* eW1 = (const float*)d_in[6];  const float* eb1 = (const float*)d_in[7];
  const float* n1W0 = (const float*)d_in[8]; const float* n1b0 = (const float*)d_in[9];
  const float* n1W1 = (const float*)d_in[10];const float* n1b1 = (const float*)d_in[11];
  const float* n2W0 = (const float*)d_in[12];const float* n2b0 = (const float*)d_in[13];
  const float* n2W1 = (const float*)d_in[14];const float* n2b1 = (const float*)d_in[15];
  const float* g1W0 = (const float*)d_in[16];const float* g1b0 = (const float*)d_in[17];
  const float* g1W1 = (const float*)d_in[18];const float* g1b1 = (const float*)d_in[19];
  const float* g2W0 = (const float*)d_in[20];const float* g2b0 = (const float*)d_in[21];
  const float* g2W1 = (const float*)d_in[22];const float* g2b1 = (const float*)d_in[23];
  const float* fW0 = (const float*)d_in[24]; const float* fb0 = (const float*)d_in[25];
  const float* fW1 = (const float*)d_in[26]; const float* fb1 = (const float*)d_in[27];

  const int* rowv = eidx;
  const int* colv = eidx + N_EDGES;

  char* ws = (char*)d_ws;
  size_t off = 0;
  auto alloc = [&](size_t bytes) -> void* {
    void* p = ws + off; off = (off + bytes + 255) & ~(size_t)255; return p;
  };
  u16*   x_b    = (u16*)alloc((size_t)N_NODES * 128 * 2);
  u16*   adjX_b = (u16*)alloc((size_t)N_NODES * 128 * 2);
  u16*   aggE_b = (u16*)alloc((size_t)N_NODES * 64 * 2);
  float* degf   = (float*)alloc((size_t)N_NODES * 4);
  int*   rowptr = (int*)alloc((size_t)(N_NODES + 1) * 4);
  int*   crow   = (int*)alloc((size_t)N_EDGES * 4);
  int*   ceid   = (int*)alloc((size_t)N_EDGES * 4);
  float* Ppart  = (float*)alloc((size_t)CGB * 8192 * 4);
  // ---- zeroed region (single memset) ----
  char*  zstart = ws + off;
  int*   cursor = (int*)alloc((size_t)N_NODES * 4);
  float* cnt    = (float*)alloc((size_t)N_NODES * 64 * 4);
  float* npool  = (float*)alloc((size_t)NB * 128 * 4);
  float* PaggE  = (float*)alloc((size_t)NB * 64 * 4);
  float* pdeg   = (float*)alloc((size_t)NB * 4);
  size_t zbytes = (size_t)((ws + off) - zstart);
  float* PadjX  = (float*)alloc((size_t)NB * 128 * 4);
  // ---- f32 weight-composition scratch ----
  float* N1a   = (float*)alloc(128 * 128 * 4);
  float* N1b   = (float*)alloc(64 * 128 * 4);
  float* N2a   = (float*)alloc(128 * 128 * 4);
  float* N2b   = (float*)alloc(128 * 128 * 4);
  float* A1    = (float*)alloc(128 * 64 * 4);
  float* B1    = (float*)alloc(128 * 64 * 4);
  float* C1    = (float*)alloc(64 * 64 * 4);
  float* G1a   = (float*)alloc(128 * 128 * 4);
  float* G1b   = (float*)alloc(64 * 128 * 4);
  float* T1    = (float*)alloc(64 * 128 * 4);
  float* U1    = (float*)alloc(128 * 128 * 4);
  float* WadjX = (float*)alloc(128 * 128 * 4);
  float* WaggE = (float*)alloc(64 * 128 * 4);
  float* Wdegx = (float*)alloc(128 * 128 * 4);
  float* c0    = (float*)alloc(64 * 4);
  float* d1    = (float*)alloc(128 * 4);
  float* d2    = (float*)alloc(128 * 4);
  float* tmpv  = (float*)alloc(128 * 4);
  float* ddeg  = (float*)alloc(128 * 4);
  float* e1    = (float*)alloc(128 * 4);
  float* bc    = (float*)alloc(192 * 4);
  float* bd    = (float*)alloc(192 * 4);
  u16*   BigWt = (u16*)alloc((size_t)192 * 448 * 2);
  (void)ws_size; (void)in_sizes; (void)n_in; (void)out_size;

  // ---- one memset for everything needing zeros ----
  hipMemsetAsync(zstart, 0, zbytes, stream);

  // x -> bf16
  k_f2b<<<(N_NODES * 128 + 255) / 256, 256, 0, stream>>>(x, x_b, N_NODES * 128);

  // ---- weight composition, level-batched ----
  {
    MMBatch L1{};
    L1.op[0]  = {n1W0, n1W1, nullptr, N1a, 128, 0,   128, 128, 128, 128};
    L1.op[1]  = {n1W0, n1W1, nullptr, N1b, 128, 128, 128, 128, 128, 64};
    L1.op[2]  = {n2W0, n2W1, nullptr, N2a, 128, 0,   128, 128, 128, 128};
    L1.op[3]  = {n2W0, n2W1, nullptr, N2b, 128, 128, 128, 128, 128, 128};
    L1.op[4]  = {eW0,  eW1,  nullptr, A1,  128, 0,   64,  128, 64,  128};
    L1.op[5]  = {eW0,  eW1,  nullptr, B1,  128, 128, 64,  128, 64,  128};
    L1.op[6]  = {eW0,  eW1,  nullptr, C1,  128, 256, 64,  128, 64,  64};
    L1.op[7]  = {g1W0, g1W1, nullptr, G1a, 128, 0,   128, 128, 128, 128};
    L1.op[8]  = {g1W0, g1W1, nullptr, G1b, 128, 128, 128, 128, 128, 64};
    L1.op[9]  = {eb0,  eW1,  eb1,     c0,  128, 0,   64,  128, 64,  1};
    L1.op[10] = {n1b0, n1W1, n1b1,    d1,  128, 0,   128, 128, 128, 1};
    L1.op[11] = {n2b0, n2W1, n2b1,    d2,  128, 0,   128, 128, 128, 1};
    L1.op[12] = {g1b0, g1W1, g1b1,    e1,  128, 0,   128, 128, 128, 1};
    k_mmb<<<dim3(128, 13), 128, 0, stream>>>(L1);

    MMBatch L2{};
    L2.op[0] = {N1b, N2b, nullptr, T1, 128, 0, 128, 128, 128, 64};
    L2.op[1] = {N1a, N2b, nullptr, U1, 128, 0, 128, 128, 128, 128};
    for (int j = 2; j < 13; ++j) L2.op[j] = {nullptr, nullptr, nullptr, nullptr, 0, 0, 0, 0, 0, 0};
    k_mmb<<<dim3(128, 2), 128, 0, stream>>>(L2);

    MMBatch L3{};
    L3.op[0] = {A1, T1, U1,      WadjX, 64,  0, 128, 64,  128, 128};
    L3.op[1] = {C1, T1, nullptr, WaggE, 64,  0, 128, 64,  128, 64};
    L3.op[2] = {B1, T1, nullptr, Wdegx, 64,  0, 128, 64,  128, 128};
    L3.op[3] = {c0, T1, nullptr, tmpv,  64,  0, 128, 64,  128, 1};
    for (int j = 4; j < 13; ++j) L3.op[j] = {nullptr, nullptr, nullptr, nullptr, 0, 0, 0, 0, 0, 0};
    k_mmb<<<dim3(128, 4), 128, 0, stream>>>(L3);

    k_mm<<<1, 128, 0, stream>>>(d1, 128, 0, N2b, 128, tmpv, ddeg, 128, 128);
  }
  k_pack_iter<<<(192 * 448 + 255) / 256, 256, 0, stream>>>(N2a, WadjX, A1, WaggE, C1, Wdegx, B1, BigWt);
  k_packbias<<<1, 192, 0, stream>>>(d2, ddeg, c0, bc, bd);

  // ---- CSR over col + cnt matrix ----
  k_hist<<<(N_EDGES + 255) / 256, 256, 0, stream>>>(colv, cursor);
  k_scan<<<1, 1024, 0, stream>>>(cursor, rowptr, cursor, degf, N_NODES);
  k_fill<<<(N_EDGES + 255) / 256, 256, 0, stream>>>(rowv, colv, cursor, crow, ceid);
  k_cnt<<<(N_EDGES + 255) / 256, 256, 0, stream>>>(rowv, colv, batch, cnt);

  const int GM = (N_NODES + 63) / 64;      // 782

  Chunks chIter;
  chIter.src[0] = x_b;    chIter.width[0] = 128; chIter.koff[0] = 0;  chIter.scl[0] = 0;
  chIter.src[1] = x_b;    chIter.width[1] = 128; chIter.koff[1] = 64; chIter.scl[1] = 0;
  chIter.src[2] = adjX_b; chIter.width[2] = 128; chIter.koff[2] = 0;  chIter.scl[2] = 0;
  chIter.src[3] = adjX_b; chIter.width[3] = 128; chIter.koff[3] = 64; chIter.scl[3] = 0;
  chIter.src[4] = aggE_b; chIter.width[4] = 64;  chIter.koff[4] = 0;  chIter.scl[4] = 0;
  chIter.src[5] = x_b;    chIter.width[5] = 128; chIter.koff[5] = 0;  chIter.scl[5] = 1;
  chIter.src[6] = x_b;    chIter.width[6] = 128; chIter.koff[6] = 64; chIter.scl[6] = 1;

  // ---- iteration 1 ----
  k_agg<true><<<2048, 256, 0, stream>>>(x_b, eattr, rowptr, crow, ceid, adjX_b, aggE_b);
  gemm_fused<64, 192, 7><<<GM, 256, 0, stream>>>(BigWt, 448, bc, bd, degf, chIter, N_NODES, 128,
                                                 x_b, aggE_b);
  // ---- iteration 2 ----
  k_agg<false><<<2048, 256, 0, stream>>>(x_b, nullptr, rowptr, crow, ceid, adjX_b, nullptr);
  gemm_fused<64, 192, 7><<<GM, 256, 0, stream>>>(BigWt, 448, bc, bd, degf, chIter, N_NODES, 128,
                                                 x_b, aggE_b);

  // ---- pooled GlobalModel path ----
  k_cntgemm<<<CGB, 256, 0, stream>>>(cnt, x_b, Ppart);
  k_pred<<<32, 256, 0, stream>>>(Ppart, PadjX);
  k_pool128b<<<(N_NODES + 127) / 128, 128, 0, stream>>>(x_b, batch, npool, N_NODES);
  k_pool64<<<(N_NODES + 127) / 128, 64, 0, stream>>>(aggE_b, batch, PaggE, N_NODES);
  k_pool1<<<(N_NODES + 127) / 128, 64, 0, stream>>>(degf, batch, pdeg, N_NODES);

  // ---- head: msg_pool + global MLP + final MLP ----
  k_head<<<NB, 256, 0, stream>>>(npool, PadjX, PaggE, pdeg, G1a, G1b, e1,
                                 g2W0, g2b0, g2W1, g2b1, fW0, fb0, fW1, fb1,
                                 (float*)d_out);
}

// Round 8
// 518.524 us; speedup vs baseline: 3.8212x; 1.3161x over previous
//
#include <hip/hip_runtime.h>
#include <hip/hip_bf16.h>

#define N_NODES 50000
#define N_EDGES 400000
#define NB 64
#define SCB 196   // ceil(N_NODES/256)

typedef unsigned short u16;
typedef unsigned int u32;
typedef __attribute__((ext_vector_type(8))) short s16x8;
typedef __attribute__((ext_vector_type(4))) float f32x4;

__device__ __forceinline__ u16 f2b(float f) {
  __hip_bfloat16 h = __float2bfloat16(f);
  return *reinterpret_cast<const u16*>(&h);
}
__device__ __forceinline__ float b2f(u16 u) {
  u32 v = ((u32)u) << 16;
  return *reinterpret_cast<const float*>(&v);
}

// ---------------- elementwise f32 -> bf16 ----------------
__global__ void k_f2b(const float* __restrict__ in, u16* __restrict__ out, int n) {
  int i = blockIdx.x * 256 + threadIdx.x;
  if (i < n) out[i] = f2b(in[i]);
}

// ---------------- batched small f32 matmuls ----------------
struct MMOp { const float* A; const float* B; const float* add; float* C;
              int lda, r0, ldb, K2, N, rows; };
struct MMBatch { MMOp op[13]; };

__global__ void k_mmb(MMBatch mb) {
  MMOp o = mb.op[blockIdx.y];
  int i = blockIdx.x;
  int n = threadIdx.x;
  if (i >= o.rows || n >= o.N) return;
  float acc = o.add ? o.add[(size_t)i * o.N + n] : 0.f;
  for (int k = 0; k < o.K2; ++k)
    acc = fmaf(o.A[(size_t)(o.r0 + i) * o.lda + k], o.B[(size_t)k * o.ldb + n], acc);
  o.C[(size_t)i * o.N + n] = acc;
}

__global__ void k_mm(const float* __restrict__ A, int lda, int r0,
                     const float* __restrict__ B, int ldb,
                     const float* __restrict__ add, float* __restrict__ C,
                     int K2, int N) {
  int i = blockIdx.x, n = threadIdx.x;
  if (n >= N) return;
  float acc = add ? add[(size_t)i * N + n] : 0.f;
  for (int k = 0; k < K2; ++k)
    acc = fmaf(A[(size_t)(r0 + i) * lda + k], B[(size_t)k * ldb + n], acc);
  C[(size_t)i * N + n] = acc;
}

// ---------------- pack composed weights (bf16, N-major rows of K) ----------------
__global__ void k_pack_iter(const float* __restrict__ N2a, const float* __restrict__ WadjX,
                            const float* __restrict__ A1, const float* __restrict__ WaggE,
                            const float* __restrict__ C1, const float* __restrict__ Wdegx,
                            const float* __restrict__ B1, u16* __restrict__ Wt) {
  int i = blockIdx.x * 256 + threadIdx.x;
  if (i >= 192 * 448) return;
  int n = i / 448, k = i % 448;
  float v;
  if (k < 128)      v = (n < 128) ? N2a[(size_t)k * 128 + n] : 0.f;
  else if (k < 256) { int kk = k - 128; v = (n < 128) ? WadjX[(size_t)kk * 128 + n] : A1[(size_t)kk * 64 + (n - 128)]; }
  else if (k < 320) { int kk = k - 256; v = (n < 128) ? WaggE[(size_t)kk * 128 + n] : C1[(size_t)kk * 64 + (n - 128)]; }
  else              { int kk = k - 320; v = (n < 128) ? Wdegx[(size_t)kk * 128 + n] : B1[(size_t)kk * 64 + (n - 128)]; }
  Wt[(size_t)n * 448 + k] = f2b(v);
}

__global__ void k_packbias(const float* __restrict__ d2, const float* __restrict__ ddeg,
                           const float* __restrict__ c0, float* __restrict__ bc,
                           float* __restrict__ bd) {
  int t = threadIdx.x;
  if (t >= 192) return;
  bc[t] = (t < 128) ? d2[t] : 0.f;
  bd[t] = (t < 128) ? ddeg[t] : c0[t - 128];
}

// ---------------- fused histogram + cnt matrix ----------------
__global__ void k_histcnt(const int* __restrict__ rowv, const int* __restrict__ colv,
                          const int* __restrict__ batch, int* __restrict__ deg,
                          float* __restrict__ cnt) {
  int e = blockIdx.x * 256 + threadIdx.x;
  if (e >= N_EDGES) return;
  int c = colv[e];
  atomicAdd(&deg[c], 1);
  atomicAdd(&cnt[(size_t)rowv[e] * 64 + batch[c]], 1.0f);
}

// ---------------- 3-phase parallel exclusive scan over deg ----------------
__global__ void k_scan1(const int* __restrict__ deg, int* __restrict__ bsum, int n) {
  __shared__ int red[256];
  int t = threadIdx.x;
  int i = blockIdx.x * 256 + t;
  red[t] = (i < n) ? deg[i] : 0;
  __syncthreads();
  for (int s = 128; s > 0; s >>= 1) {
    if (t < s) red[t] += red[t + s];
    __syncthreads();
  }
  if (t == 0) bsum[blockIdx.x] = red[0];
}

__global__ void k_scan2(int* __restrict__ bsum, int nb) {
  __shared__ int sh[256];
  int t = threadIdx.x;
  sh[t] = (t < nb) ? bsum[t] : 0;
  __syncthreads();
  for (int d = 1; d < 256; d <<= 1) {
    int v = (t >= d) ? sh[t - d] : 0;
    __syncthreads();
    sh[t] += v;
    __syncthreads();
  }
  if (t < nb) bsum[t] = sh[t];   // inclusive block prefix
}

// reads deg (aliased with cursor), writes rowptr/cursor/degf
__global__ void k_scan3(const int* __restrict__ deg, const int* __restrict__ bsum,
                        int* __restrict__ rowptr, int* __restrict__ cursor,
                        float* __restrict__ degf, int n) {
  __shared__ int sh[256];
  int t = threadIdx.x;
  int i = blockIdx.x * 256 + t;
  int d = (i < n) ? deg[i] : 0;
  sh[t] = d;
  __syncthreads();
  for (int s = 1; s < 256; s <<= 1) {
    int v = (t >= s) ? sh[t - s] : 0;
    __syncthreads();
    sh[t] += v;
    __syncthreads();
  }
  int base = (blockIdx.x > 0) ? bsum[blockIdx.x - 1] : 0;
  int ex = base + sh[t] - d;
  if (i < n) {
    rowptr[i] = ex;
    cursor[i] = ex;
    degf[i] = (float)d;
    if (i == n - 1) rowptr[n] = ex + d;
  }
}

__global__ void k_fill(const int* __restrict__ rowv, const int* __restrict__ colv,
                       int* __restrict__ cursor, int* __restrict__ crow, int* __restrict__ ceid) {
  int i = blockIdx.x * 256 + threadIdx.x;
  if (i >= N_EDGES) return;
  int pos = atomicAdd(&cursor[colv[i]], 1);
  crow[pos] = rowv[i];
  ceid[pos] = i;
}

// ---------------- Ppart[blk][b*128+c] = sum_{v in span} cnt[v][b] * x2[v][c] ----------------
#define CGB 512
__global__ __launch_bounds__(256)
void k_cntgemm(const float* __restrict__ cnt, const u16* __restrict__ xb,
               float* __restrict__ Ppart) {
  __shared__ float cs[8][64];
  int t = threadIdx.x, c = t & 127, half = t >> 7;
  float acc[32];
#pragma unroll
  for (int q = 0; q < 32; ++q) acc[q] = 0.f;
  int span = (N_NODES + CGB - 1) / CGB;
  int v0 = blockIdx.x * span;
  int v1 = v0 + span; if (v1 > N_NODES) v1 = N_NODES;
  for (int vt = v0; vt < v1; vt += 8) {
    int nv = v1 - vt; if (nv > 8) nv = 8;
    for (int idx = t; idx < nv * 64; idx += 256)
      cs[idx >> 6][idx & 63] = cnt[(size_t)(vt + (idx >> 6)) * 64 + (idx & 63)];
    __syncthreads();
    for (int j = 0; j < nv; ++j) {
      float xv = b2f(xb[(size_t)(vt + j) * 128 + c]);
#pragma unroll
      for (int q = 0; q < 32; ++q) acc[q] = fmaf(cs[j][half * 32 + q], xv, acc[q]);
    }
    __syncthreads();
  }
#pragma unroll
  for (int q = 0; q < 32; ++q)
    Ppart[(size_t)blockIdx.x * 8192 + (size_t)(half * 32 + q) * 128 + c] = acc[q];
}

__global__ void k_pred(const float* __restrict__ Ppart, float* __restrict__ P) {
  int i = blockIdx.x * 256 + threadIdx.x;   // 8192 threads
  float s = 0.f;
  for (int k = 0; k < CGB; ++k) s += Ppart[(size_t)k * 8192 + i];
  P[i] = s;
}

// ---------------- CSR gather segment-sums (4-way unrolled) ----------------
template<bool DOE>
__global__ void k_agg(const u16* __restrict__ xb, const float* __restrict__ eaf,
                      const int* __restrict__ rowptr, const int* __restrict__ crow,
                      const int* __restrict__ ceid,
                      u16* __restrict__ outX, u16* __restrict__ outE) {
  int wpb = blockDim.x >> 6;
  int w = blockIdx.x * wpb + (threadIdx.x >> 6);
  int l = threadIdx.x & 63;
  int nw = gridDim.x * wpb;
  for (int v = w; v < N_NODES; v += nw) {
    int s = rowptr[v], e1 = rowptr[v + 1];
    float ax0 = 0.f, ax1 = 0.f, ae = 0.f;
    int i = s;
    for (; i + 3 < e1; i += 4) {
      int r0 = crow[i], r1 = crow[i + 1], r2 = crow[i + 2], r3 = crow[i + 3];
      u32 a0 = *reinterpret_cast<const u32*>(&xb[(size_t)r0 * 128 + l * 2]);
      u32 a1 = *reinterpret_cast<const u32*>(&xb[(size_t)r1 * 128 + l * 2]);
      u32 a2 = *reinterpret_cast<const u32*>(&xb[(size_t)r2 * 128 + l * 2]);
      u32 a3 = *reinterpret_cast<const u32*>(&xb[(size_t)r3 * 128 + l * 2]);
      float e0, ev1, ev2, ev3;
      if (DOE) {
        int q0 = ceid[i], q1 = ceid[i + 1], q2 = ceid[i + 2], q3 = ceid[i + 3];
        e0  = eaf[(size_t)q0 * 64 + l];
        ev1 = eaf[(size_t)q1 * 64 + l];
        ev2 = eaf[(size_t)q2 * 64 + l];
        ev3 = eaf[(size_t)q3 * 64 + l];
      }
      ax0 += b2f((u16)(a0 & 0xffff)) + b2f((u16)(a1 & 0xffff))
           + b2f((u16)(a2 & 0xffff)) + b2f((u16)(a3 & 0xffff));
      ax1 += b2f((u16)(a0 >> 16)) + b2f((u16)(a1 >> 16))
           + b2f((u16)(a2 >> 16)) + b2f((u16)(a3 >> 16));
      if (DOE) ae += e0 + ev1 + ev2 + ev3;
    }
    for (; i < e1; ++i) {
      u32 a = *reinterpret_cast<const u32*>(&xb[(size_t)crow[i] * 128 + l * 2]);
      ax0 += b2f((u16)(a & 0xffff));
      ax1 += b2f((u16)(a >> 16));
      if (DOE) ae += eaf[(size_t)ceid[i] * 64 + l];
    }
    u32 pk = ((u32)f2b(ax1) << 16) | (u32)f2b(ax0);
    *reinterpret_cast<u32*>(&outX[(size_t)v * 128 + l * 2]) = pk;
    if (DOE) outE[(size_t)v * 64 + l] = f2b(ae);
  }
}

// ---------------- fused node GEMM over concatenated K-chunks of 64 ----------------
struct Chunks { const u16* src[7]; int width[7]; int koff[7]; int scl[7]; };

template<int BM, int BN, int NCH>
__global__ __launch_bounds__(256)
void gemm_fused(const u16* __restrict__ Wt, int KTOT,
                const float* __restrict__ bc, const float* __restrict__ bd,
                const float* __restrict__ degf, Chunks ch, int M, int SPLIT,
                u16* __restrict__ outb0, u16* __restrict__ outb1)
{
  constexpr int LDA = 72;
  constexpr int BP = BN / 64;
  constexpr int RF = BM / 64;
  constexpr int AE = BM / 4;
  constexpr int AV = AE / 8;
  __shared__ u16 As[BM * LDA];
  __shared__ u16 Bs[BN * LDA];

  const int t = threadIdx.x;
  const int wv = t >> 6, lane = t & 63, lr = lane & 15, lg = lane >> 4;
  const int bm0 = blockIdx.x * BM;
  const int wb = wv * (BM / 4);

  f32x4 acc[RF][BN / 16];
#pragma unroll
  for (int a = 0; a < RF; ++a)
#pragma unroll
    for (int b = 0; b < BN / 16; ++b) acc[a][b] = (f32x4){0.f, 0.f, 0.f, 0.f};

  const int ar = t & (BM - 1);
  const int ako = (t / BM) * AE;
  int agrow = bm0 + ar;
  if (agrow >= M) agrow = M - 1;
  const float dg_a = degf[agrow];

  const int br0 = t >> 2;
  const int bo  = (t & 3) * 16;

#pragma unroll
  for (int c = 0; c < NCH; ++c) {
    const u16* ap = ch.src[c] + (size_t)agrow * ch.width[c] + ch.koff[c] + ako;
    uint4 av[AV];
#pragma unroll
    for (int j = 0; j < AV; ++j) av[j] = *reinterpret_cast<const uint4*>(ap + j * 8);
    if (ch.scl[c]) {
#pragma unroll
      for (int j = 0; j < AV; ++j) {
        u32* p = reinterpret_cast<u32*>(&av[j]);
#pragma unroll
        for (int q = 0; q < 4; ++q) {
          u32 w = p[q];
          float lo = b2f((u16)(w & 0xffff)) * dg_a;
          float hi = b2f((u16)(w >> 16)) * dg_a;
          p[q] = ((u32)f2b(hi) << 16) | (u32)f2b(lo);
        }
      }
    }
    uint4 bv[BP * 2];
#pragma unroll
    for (int p = 0; p < BP; ++p) {
      const u16* bp = Wt + (size_t)(p * 64 + br0) * KTOT + c * 64 + bo;
      bv[p * 2]     = *reinterpret_cast<const uint4*>(bp);
      bv[p * 2 + 1] = *reinterpret_cast<const uint4*>(bp + 8);
    }
    __syncthreads();
#pragma unroll
    for (int j = 0; j < AV; ++j)
      *reinterpret_cast<uint4*>(&As[ar * LDA + ako + j * 8]) = av[j];
#pragma unroll
    for (int p = 0; p < BP; ++p) {
      *reinterpret_cast<uint4*>(&Bs[(p * 64 + br0) * LDA + bo])     = bv[p * 2];
      *reinterpret_cast<uint4*>(&Bs[(p * 64 + br0) * LDA + bo + 8]) = bv[p * 2 + 1];
    }
    __syncthreads();

#pragma unroll
    for (int kk = 0; kk < 64; kk += 32) {
      s16x8 af[RF];
#pragma unroll
      for (int rf = 0; rf < RF; ++rf)
        af[rf] = *reinterpret_cast<const s16x8*>(&As[(wb + rf * 16 + lr) * LDA + kk + lg * 8]);
#pragma unroll
      for (int f = 0; f < BN / 16; ++f) {
        s16x8 bf = *reinterpret_cast<const s16x8*>(&Bs[(f * 16 + lr) * LDA + kk + lg * 8]);
#pragma unroll
        for (int rf = 0; rf < RF; ++rf)
          acc[rf][f] = __builtin_amdgcn_mfma_f32_16x16x32_bf16(af[rf], bf, acc[rf][f], 0, 0, 0);
      }
    }
  }

  float bcv[BN / 16], bdv[BN / 16];
#pragma unroll
  for (int f = 0; f < BN / 16; ++f) {
    int col = f * 16 + lr;
    bcv[f] = bc ? bc[col] : 0.f;
    bdv[f] = bd ? bd[col] : 0.f;
  }

#pragma unroll
  for (int rf = 0; rf < RF; ++rf)
#pragma unroll
    for (int rr = 0; rr < 4; ++rr) {
      int grow = bm0 + wb + rf * 16 + lg * 4 + rr;
      if (grow >= M) continue;
      float dgr = degf[grow];
#pragma unroll
      for (int f = 0; f < BN / 16; ++f) {
        int col = f * 16 + lr;
        float v = acc[rf][f][rr] + bcv[f] + dgr * bdv[f];
        if (col < SPLIT) {
          outb0[(size_t)grow * SPLIT + col] = f2b(v);
        } else {
          outb1[(size_t)grow * (BN - SPLIT) + (col - SPLIT)] = f2b(v);
        }
      }
    }
}

// ---------------- fused sorted-batch pooling: x(128) + aggE(64) + deg(1) ----------------
__global__ void k_poolall(const u16* __restrict__ xb, const u16* __restrict__ aggE,
                          const float* __restrict__ degf, const int* __restrict__ batch,
                          float* __restrict__ npool, float* __restrict__ PaggE,
                          float* __restrict__ pdeg, int n) {
  int t = threadIdx.x;           // 256
  int n0 = blockIdx.x * 128;
  if (n0 >= n) return;
  int n1 = n0 + 128; if (n1 > n) n1 = n;
  float acc = 0.f;
  int cur = batch[n0];
  for (int i = n0; i < n1; ++i) {
    int bi = batch[i];
    if (bi != cur) {
      if (t < 128) atomicAdd(&npool[cur * 128 + t], acc);
      else if (t < 192) atomicAdd(&PaggE[cur * 64 + (t - 128)], acc);
      else if (t == 192) atomicAdd(&pdeg[cur], acc);
      acc = 0.f; cur = bi;
    }
    if (t < 128) acc += b2f(xb[(size_t)i * 128 + t]);
    else if (t < 192) acc += b2f(aggE[(size_t)i * 64 + (t - 128)]);
    else if (t == 192) acc += degf[i];
  }
  if (t < 128) atomicAdd(&npool[cur * 128 + t], acc);
  else if (t < 192) atomicAdd(&PaggE[cur * 64 + (t - 128)], acc);
  else if (t == 192) atomicAdd(&pdeg[cur], acc);
}

// ---------------- head: msg_pool + global MLP + final MLP, one block per graph ----------------
__global__ void k_head(const float* __restrict__ npool, const float* __restrict__ PadjX,
                       const float* __restrict__ PaggE, const float* __restrict__ pdeg,
                       const float* __restrict__ G1a, const float* __restrict__ G1b,
                       const float* __restrict__ e1,
                       const float* __restrict__ g2W0, const float* __restrict__ g2b0,
                       const float* __restrict__ g2W1, const float* __restrict__ g2b1,
                       const float* __restrict__ fW0, const float* __restrict__ fb0,
                       const float* __restrict__ fW1, const float* __restrict__ fb1,
                       float* __restrict__ out) {
  __shared__ float r0[256], r1[128], r2[128], r3[256], red[256];
  int b = blockIdx.x, t = threadIdx.x;
  if (t < 128) {
    float a = pdeg[b] * e1[t];
    for (int k = 0; k < 128; ++k) a = fmaf(PadjX[(size_t)b * 128 + k], G1a[(size_t)k * 128 + t], a);
    for (int k = 0; k < 64;  ++k) a = fmaf(PaggE[(size_t)b * 64 + k],  G1b[(size_t)k * 128 + t], a);
    r0[128 + t] = a;
    r0[t] = npool[(size_t)b * 128 + t];
  }
  __syncthreads();
  if (t < 128) {
    float a = g2b0[t];
    for (int k = 0; k < 256; ++k) a = fmaf(r0[k], g2W0[(size_t)k * 128 + t], a);
    r1[t] = a;
  }
  __syncthreads();
  if (t < 128) {
    float a = g2b1[t];
    for (int k = 0; k < 128; ++k) a = fmaf(r1[k], g2W1[(size_t)k * 128 + t], a);
    r2[t] = a;
  }
  __syncthreads();
  {
    float a = fb0[t];
    for (int k = 0; k < 128; ++k) a = fmaf(r2[k], fW0[(size_t)k * 256 + t], a);
    r3[t] = a;
  }
  __syncthreads();
  red[t] = r3[t] * fW1[t];
  __syncthreads();
  for (int s = 128; s > 0; s >>= 1) {
    if (t < s) red[t] += red[t + s];
    __syncthreads();
  }
  if (t == 0) out[b] = red[0] + fb1[0];
}

extern "C" void kernel_launch(void* const* d_in, const int* in_sizes, int n_in,
                              void* d_out, int out_size, void* d_ws, size_t ws_size,
                              hipStream_t stream) {
  const float* x     = (const float*)d_in[0];
  const int*   eidx  = (const int*)d_in[1];
  const float* eattr = (const float*)d_in[2];
  const int*   batch = (const int*)d_in[3];
  const float* eW0 = (const float*)d_in[4];  const float* eb0 = (const float*)d_in[5];
  const float* eW1 = (const float*)d_in[6];  const float* eb1 = (const float*)d_in[7];
  const float* n1W0 = (const float*)d_in[8]; const float* n1b0 = (const float*)d_in[9];
  const float* n1W1 = (const float*)d_in[10];const float* n1b1 = (const float*)d_in[11];
  const float* n2W0 = (const float*)d_in[12];const float* n2b0 = (const float*)d_in[13];
  const float* n2W1 = (const float*)d_in[14];const float* n2b1 = (const float*)d_in[15];
  const float* g1W0 = (const float*)d_in[16];const float* g1b0 = (const float*)d_in[17];
  const float* g1W1 = (const float*)d_in[18];const float* g1b1 = (const float*)d_in[19];
  const float* g2W0 = (const float*)d_in[20];const float* g2b0 = (const float*)d_in[21];
  const float* g2W1 = (const float*)d_in[22];const float* g2b1 = (const float*)d_in[23];
  const float* fW0 = (const float*)d_in[24]; const float* fb0 = (const float*)d_in[25];
  const float* fW1 = (const float*)d_in[26]; const float* fb1 = (const float*)d_in[27];

  const int* rowv = eidx;
  const int* colv = eidx + N_EDGES;

  char* ws = (char*)d_ws;
  size_t off = 0;
  auto alloc = [&](size_t bytes) -> void* {
    void* p = ws + off; off = (off + bytes + 255) & ~(size_t)255; return p;
  };
  u16*   x_b    = (u16*)alloc((size_t)N_NODES * 128 * 2);
  u16*   adjX_b = (u16*)alloc((size_t)N_NODES * 128 * 2);
  u16*   aggE_b = (u16*)alloc((size_t)N_NODES * 64 * 2);
  float* degf   = (float*)alloc((size_t)N_NODES * 4);
  int*   rowptr = (int*)alloc((size_t)(N_NODES + 1) * 4);
  int*   crow   = (int*)alloc((size_t)N_EDGES * 4);
  int*   ceid   = (int*)alloc((size_t)N_EDGES * 4);
  int*   bsum   = (int*)alloc((size_t)256 * 4);
  float* Ppart  = (float*)alloc((size_t)CGB * 8192 * 4);
  // ---- zeroed region (single memset) ----
  char*  zstart = ws + off;
  int*   cursor = (int*)alloc((size_t)N_NODES * 4);
  float* cnt    = (float*)alloc((size_t)N_NODES * 64 * 4);
  float* npool  = (float*)alloc((size_t)NB * 128 * 4);
  float* PaggE  = (float*)alloc((size_t)NB * 64 * 4);
  float* pdeg   = (float*)alloc((size_t)NB * 4);
  size_t zbytes = (size_t)((ws + off) - zstart);
  float* PadjX  = (float*)alloc((size_t)NB * 128 * 4);
  // ---- f32 weight-composition scratch ----
  float* N1a   = (float*)alloc(128 * 128 * 4);
  float* N1b   = (float*)alloc(64 * 128 * 4);
  float* N2a   = (float*)alloc(128 * 128 * 4);
  float* N2b   = (float*)alloc(128 * 128 * 4);
  float* A1    = (float*)alloc(128 * 64 * 4);
  float* B1    = (float*)alloc(128 * 64 * 4);
  float* C1    = (float*)alloc(64 * 64 * 4);
  float* G1a   = (float*)alloc(128 * 128 * 4);
  float* G1b   = (float*)alloc(64 * 128 * 4);
  float* T1    = (float*)alloc(64 * 128 * 4);
  float* U1    = (float*)alloc(128 * 128 * 4);
  float* WadjX = (float*)alloc(128 * 128 * 4);
  float* WaggE = (float*)alloc(64 * 128 * 4);
  float* Wdegx = (float*)alloc(128 * 128 * 4);
  float* c0    = (float*)alloc(64 * 4);
  float* d1    = (float*)alloc(128 * 4);
  float* d2    = (float*)alloc(128 * 4);
  float* tmpv  = (float*)alloc(128 * 4);
  float* ddeg  = (float*)alloc(128 * 4);
  float* e1    = (float*)alloc(128 * 4);
  float* bc    = (float*)alloc(192 * 4);
  float* bd    = (float*)alloc(192 * 4);
  u16*   BigWt = (u16*)alloc((size_t)192 * 448 * 2);
  (void)ws_size; (void)in_sizes; (void)n_in; (void)out_size;

  // ---- one memset for everything needing zeros ----
  hipMemsetAsync(zstart, 0, zbytes, stream);

  // x -> bf16
  k_f2b<<<(N_NODES * 128 + 255) / 256, 256, 0, stream>>>(x, x_b, N_NODES * 128);

  // ---- weight composition, level-batched ----
  {
    MMBatch L1{};
    L1.op[0]  = {n1W0, n1W1, nullptr, N1a, 128, 0,   128, 128, 128, 128};
    L1.op[1]  = {n1W0, n1W1, nullptr, N1b, 128, 128, 128, 128, 128, 64};
    L1.op[2]  = {n2W0, n2W1, nullptr, N2a, 128, 0,   128, 128, 128, 128};
    L1.op[3]  = {n2W0, n2W1, nullptr, N2b, 128, 128, 128, 128, 128, 128};
    L1.op[4]  = {eW0,  eW1,  nullptr, A1,  128, 0,   64,  128, 64,  128};
    L1.op[5]  = {eW0,  eW1,  nullptr, B1,  128, 128, 64,  128, 64,  128};
    L1.op[6]  = {eW0,  eW1,  nullptr, C1,  128, 256, 64,  128, 64,  64};
    L1.op[7]  = {g1W0, g1W1, nullptr, G1a, 128, 0,   128, 128, 128, 128};
    L1.op[8]  = {g1W0, g1W1, nullptr, G1b, 128, 128, 128, 128, 128, 64};
    L1.op[9]  = {eb0,  eW1,  eb1,     c0,  128, 0,   64,  128, 64,  1};
    L1.op[10] = {n1b0, n1W1, n1b1,    d1,  128, 0,   128, 128, 128, 1};
    L1.op[11] = {n2b0, n2W1, n2b1,    d2,  128, 0,   128, 128, 128, 1};
    L1.op[12] = {g1b0, g1W1, g1b1,    e1,  128, 0,   128, 128, 128, 1};
    k_mmb<<<dim3(128, 13), 128, 0, stream>>>(L1);

    MMBatch L2{};
    L2.op[0] = {N1b, N2b, nullptr, T1, 128, 0, 128, 128, 128, 64};
    L2.op[1] = {N1a, N2b, nullptr, U1, 128, 0, 128, 128, 128, 128};
    for (int j = 2; j < 13; ++j) L2.op[j] = {nullptr, nullptr, nullptr, nullptr, 0, 0, 0, 0, 0, 0};
    k_mmb<<<dim3(128, 2), 128, 0, stream>>>(L2);

    MMBatch L3{};
    L3.op[0] = {A1, T1, U1,      WadjX, 64,  0, 128, 64,  128, 128};
    L3.op[1] = {C1, T1, nullptr, WaggE, 64,  0, 128, 64,  128, 64};
    L3.op[2] = {B1, T1, nullptr, Wdegx, 64,  0, 128, 64,  128, 128};
    L3.op[3] = {c0, T1, nullptr, tmpv,  64,  0, 128, 64,  128, 1};
    for (int j = 4; j < 13; ++j) L3.op[j] = {nullptr, nullptr, nullptr, nullptr, 0, 0, 0, 0, 0, 0};
    k_mmb<<<dim3(128, 4), 128, 0, stream>>>(L3);

    k_mm<<<1, 128, 0, stream>>>(d1, 128, 0, N2b, 128, tmpv, ddeg, 128, 128);
  }
  k_pack_iter<<<(192 * 448 + 255) / 256, 256, 0, stream>>>(N2a, WadjX, A1, WaggE, C1, Wdegx, B1, BigWt);
  k_packbias<<<1, 192, 0, stream>>>(d2, ddeg, c0, bc, bd);

  // ---- CSR over col + cnt matrix (parallel scan) ----
  k_histcnt<<<(N_EDGES + 255) / 256, 256, 0, stream>>>(rowv, colv, batch, cursor, cnt);
  k_scan1<<<SCB, 256, 0, stream>>>(cursor, bsum, N_NODES);
  k_scan2<<<1, 256, 0, stream>>>(bsum, SCB);
  k_scan3<<<SCB, 256, 0, stream>>>(cursor, bsum, rowptr, cursor, degf, N_NODES);
  k_fill<<<(N_EDGES + 255) / 256, 256, 0, stream>>>(rowv, colv, cursor, crow, ceid);

  const int GM = (N_NODES + 63) / 64;      // 782

  Chunks chIter;
  chIter.src[0] = x_b;    chIter.width[0] = 128; chIter.koff[0] = 0;  chIter.scl[0] = 0;
  chIter.src[1] = x_b;    chIter.width[1] = 128; chIter.koff[1] = 64; chIter.scl[1] = 0;
  chIter.src[2] = adjX_b; chIter.width[2] = 128; chIter.koff[2] = 0;  chIter.scl[2] = 0;
  chIter.src[3] = adjX_b; chIter.width[3] = 128; chIter.koff[3] = 64; chIter.scl[3] = 0;
  chIter.src[4] = aggE_b; chIter.width[4] = 64;  chIter.koff[4] = 0;  chIter.scl[4] = 0;
  chIter.src[5] = x_b;    chIter.width[5] = 128; chIter.koff[5] = 0;  chIter.scl[5] = 1;
  chIter.src[6] = x_b;    chIter.width[6] = 128; chIter.koff[6] = 64; chIter.scl[6] = 1;

  // ---- iteration 1 ----
  k_agg<true><<<2048, 256, 0, stream>>>(x_b, eattr, rowptr, crow, ceid, adjX_b, aggE_b);
  gemm_fused<64, 192, 7><<<GM, 256, 0, stream>>>(BigWt, 448, bc, bd, degf, chIter, N_NODES, 128,
                                                 x_b, aggE_b);
  // ---- iteration 2 ----
  k_agg<false><<<2048, 256, 0, stream>>>(x_b, nullptr, rowptr, crow, ceid, adjX_b, nullptr);
  gemm_fused<64, 192, 7><<<GM, 256, 0, stream>>>(BigWt, 448, bc, bd, degf, chIter, N_NODES, 128,
                                                 x_b, aggE_b);

  // ---- pooled GlobalModel path ----
  k_cntgemm<<<CGB, 256, 0, stream>>>(cnt, x_b, Ppart);
  k_pred<<<32, 256, 0, stream>>>(Ppart, PadjX);
  k_poolall<<<(N_NODES + 127) / 128, 256, 0, stream>>>(x_b, aggE_b, degf, batch,
                                                       npool, PaggE, pdeg, N_NODES);

  // ---- head: msg_pool + global MLP + final MLP ----
  k_head<<<NB, 256, 0, stream>>>(npool, PadjX, PaggE, pdeg, G1a, G1b, e1,
                                 g2W0, g2b0, g2W1, g2b1, fW0, fb0, fW1, fb1,
                                 (float*)d_out);
}